// Round 1
// baseline (1906.707 us; speedup 1.0000x reference)
//
#include <hip/hip_runtime.h>

#define N_NODES 30000
#define N_EDGES 480000

// ================= GEMM 64x64 tile, f32, K=256 =================
// MODE 0: feat = A@B; epilogue computes el/er (col-tile == head, DH=64)
// MODE 1: out = A@B + t@Wp1 + bo@Wp2 + bp, strided store into d_out
template<int MODE>
__global__ __launch_bounds__(256)
void gemm_kernel(const float* __restrict__ A, const float* __restrict__ B,
                 float* __restrict__ C, int M,
                 const float* __restrict__ al, const float* __restrict__ ar,
                 float* __restrict__ el, float* __restrict__ er,
                 const float* __restrict__ tvec, const float* __restrict__ bvec,
                 const float* __restrict__ Wp1, const float* __restrict__ Wp2,
                 const float* __restrict__ bp, int ldc, int coff)
{
  __shared__ float As[16][65];
  __shared__ float Bs[16][64];
  __shared__ float W1s[8][64];
  __shared__ float W2s[8][64];

  const int tid = threadIdx.x;
  const int tx = tid & 15, ty = tid >> 4;
  const int bm = blockIdx.x * 64;
  const int ct = blockIdx.y;      // col tile == head (MODE 0)
  const int bn = ct * 64;

  if (MODE == 1) {
    if (tid < 128) {
      int r = tid >> 4, c4 = (tid & 15) * 4;
      *(float4*)&W1s[r][c4] = *(const float4*)&Wp1[r * 256 + bn + c4];
    } else {
      int t2 = tid - 128;
      int r = t2 >> 4, c4 = (t2 & 15) * 4;
      *(float4*)&W2s[r][c4] = *(const float4*)&Wp2[r * 256 + bn + c4];
    }
  }

  const int arow = tid >> 2, acol = (tid & 3) * 4;
  const int brow = tid >> 4, bcol = (tid & 15) * 4;
  const bool arow_ok = (bm + arow) < M;
  const float* Aptr = A + (size_t)(bm + arow) * 256 + acol;
  const float* Bptr = B + (size_t)brow * 256 + bn + bcol;

  float acc[4][4] = {};

  for (int k0 = 0; k0 < 256; k0 += 16) {
    float4 av = make_float4(0.f, 0.f, 0.f, 0.f);
    if (arow_ok) av = *(const float4*)(Aptr + k0);
    float4 bv = *(const float4*)(Bptr + (size_t)k0 * 256);
    __syncthreads();
    As[acol + 0][arow] = av.x;
    As[acol + 1][arow] = av.y;
    As[acol + 2][arow] = av.z;
    As[acol + 3][arow] = av.w;
    *(float4*)&Bs[brow][bcol] = bv;
    __syncthreads();
#pragma unroll
    for (int kk = 0; kk < 16; ++kk) {
      float4 b4 = *(const float4*)&Bs[kk][tx * 4];
      float bb4[4] = {b4.x, b4.y, b4.z, b4.w};
#pragma unroll
      for (int i = 0; i < 4; ++i) {
        float a = As[kk][ty * 4 + i];
#pragma unroll
        for (int j = 0; j < 4; ++j) acc[i][j] = fmaf(a, bb4[j], acc[i][j]);
      }
    }
  }

  if (MODE == 0) {
    float alv[4], arv[4];
#pragma unroll
    for (int j = 0; j < 4; ++j) {
      alv[j] = al[bn + tx * 4 + j];
      arv[j] = ar[bn + tx * 4 + j];
    }
#pragma unroll
    for (int i = 0; i < 4; ++i) {
      int row = bm + ty * 4 + i;
      float pe = 0.f, pr = 0.f;
#pragma unroll
      for (int j = 0; j < 4; ++j) {
        pe = fmaf(acc[i][j], alv[j], pe);
        pr = fmaf(acc[i][j], arv[j], pr);
      }
#pragma unroll
      for (int o = 8; o >= 1; o >>= 1) {
        pe += __shfl_xor(pe, o, 64);
        pr += __shfl_xor(pr, o, 64);
      }
      if (row < M) {
        if (tx == 0) {
          el[row * 4 + ct] = pe;
          er[row * 4 + ct] = pr;
        }
        float4 st = make_float4(acc[i][0], acc[i][1], acc[i][2], acc[i][3]);
        *(float4*)&C[(size_t)row * 256 + bn + tx * 4] = st;
      }
    }
  } else {
    float bpv[4];
#pragma unroll
    for (int j = 0; j < 4; ++j) bpv[j] = bp[bn + tx * 4 + j];
#pragma unroll
    for (int i = 0; i < 4; ++i) {
      int row = bm + ty * 4 + i;
      if (row >= M) continue;
      float4 tlo = *(const float4*)&tvec[(size_t)row * 8];
      float4 thi = *(const float4*)&tvec[(size_t)row * 8 + 4];
      float4 blo = *(const float4*)&bvec[(size_t)row * 8];
      float4 bhi = *(const float4*)&bvec[(size_t)row * 8 + 4];
      float tv8[8] = {tlo.x, tlo.y, tlo.z, tlo.w, thi.x, thi.y, thi.z, thi.w};
      float bv8[8] = {blo.x, blo.y, blo.z, blo.w, bhi.x, bhi.y, bhi.z, bhi.w};
      float outv[4];
#pragma unroll
      for (int j = 0; j < 4; ++j) {
        float v = acc[i][j] + bpv[j];
        int c = tx * 4 + j;
#pragma unroll
        for (int k = 0; k < 8; ++k) {
          v = fmaf(tv8[k], W1s[k][c], v);
          v = fmaf(bv8[k], W2s[k][c], v);
        }
        outv[j] = v;
      }
      *(float4*)&C[(size_t)row * ldc + coff + bn + tx * 4] =
          make_float4(outv[0], outv[1], outv[2], outv[3]);
    }
  }
}

// ============== per-edge: exp(leakyrelu(el[s]+er[d])), denom+count atomics ==============
__global__ void edge_pass_kernel(const int* __restrict__ src, const int* __restrict__ dst,
                                 const float* __restrict__ ew, const float* __restrict__ el,
                                 const float* __restrict__ er, float* __restrict__ a_un,
                                 float* denom, int* counts, int ne)
{
  int e = blockIdx.x * 256 + threadIdx.x;
  if (e >= ne) return;
  int s = src[e], d = dst[e];
  float w = ew[e];
  float4 l4 = *(const float4*)&el[(size_t)s * 4];
  float4 r4 = *(const float4*)&er[(size_t)d * 4];
  float v0 = l4.x + r4.x; v0 = v0 > 0.f ? v0 : 0.2f * v0;
  float v1 = l4.y + r4.y; v1 = v1 > 0.f ? v1 : 0.2f * v1;
  float v2 = l4.z + r4.z; v2 = v2 > 0.f ? v2 : 0.2f * v2;
  float v3 = l4.w + r4.w; v3 = v3 > 0.f ? v3 : 0.2f * v3;
  float x0 = __expf(v0), x1 = __expf(v1), x2 = __expf(v2), x3 = __expf(v3);
  *(float4*)&a_un[(size_t)e * 4] = make_float4(x0 * w, x1 * w, x2 * w, x3 * w);
  atomicAdd(&denom[d * 4 + 0], x0);
  atomicAdd(&denom[d * 4 + 1], x1);
  atomicAdd(&denom[d * 4 + 2], x2);
  atomicAdd(&denom[d * 4 + 3], x3);
  atomicAdd(&counts[d], 1);
}

// ============== single-block scan over counts -> offsets + cursor (in place) ==============
__global__ __launch_bounds__(1024)
void scan_kernel(int* __restrict__ cc, int* __restrict__ off, int n, int total)
{
  __shared__ int wsum[16];
  __shared__ int woff[16];
  __shared__ int s_carry, s_chunk;
  int tid = threadIdx.x;
  int lane = tid & 63, wid = tid >> 6;
  if (tid == 0) s_carry = 0;
  __syncthreads();
  for (int base = 0; base < n; base += 1024) {
    int i = base + tid;
    int v = (i < n) ? cc[i] : 0;
    int x = v;
#pragma unroll
    for (int s = 1; s < 64; s <<= 1) {
      int y = __shfl_up(x, s, 64);
      if (lane >= s) x += y;
    }
    if (lane == 63) wsum[wid] = x;
    __syncthreads();
    if (wid == 0 && lane < 16) {
      int ws_ = wsum[lane];
      int xx = ws_;
#pragma unroll
      for (int s = 1; s < 16; s <<= 1) {
        int y = __shfl_up(xx, s, 64);
        if (lane >= s) xx += y;
      }
      woff[lane] = xx - ws_;
      if (lane == 15) s_chunk = xx;
    }
    __syncthreads();
    int excl = s_carry + woff[wid] + (x - v);
    if (i < n) { off[i] = excl; cc[i] = excl; }
    __syncthreads();
    if (tid == 0) s_carry += s_chunk;
    __syncthreads();
  }
  if (tid == 0) off[n] = total;
}

// ============== CSR fill ==============
__global__ void fill_kernel(const int* __restrict__ dst, int* cursor,
                            int* __restrict__ eid, int ne)
{
  int e = blockIdx.x * 256 + threadIdx.x;
  if (e >= ne) return;
  int p = atomicAdd(&cursor[dst[e]], 1);
  eid[p] = e;
}

// ============== per-dst aggregation: gat[n] = sum a*feat[src] + b ==============
__global__ __launch_bounds__(256)
void aggregate_kernel(const int* __restrict__ off, const int* __restrict__ eid,
                      const int* __restrict__ src, const float* __restrict__ a_un,
                      const float* __restrict__ denom, const float* __restrict__ feat,
                      const float* __restrict__ bias, float* __restrict__ gat, int n_nodes)
{
  int n = blockIdx.x;
  int tid = threadIdx.x;
  int w = tid >> 6;
  __shared__ int s_src[256];
  __shared__ float s_coef[256][4];
  int e0 = off[n], e1 = off[n + 1];
  float dn = denom[(size_t)n * 4 + w];
  float invd = (dn != 0.f) ? 1.f / dn : 0.f;
  float acc = 0.f;
  for (int base = e0; base < e1; base += 256) {
    int cnt = min(256, e1 - base);
    __syncthreads();
    if (tid < cnt) {
      int e = eid[base + tid];
      s_src[tid] = src[e];
      float4 au = *(const float4*)&a_un[(size_t)e * 4];
      s_coef[tid][0] = au.x; s_coef[tid][1] = au.y;
      s_coef[tid][2] = au.z; s_coef[tid][3] = au.w;
    }
    __syncthreads();
    int k = 0;
    for (; k + 4 <= cnt; k += 4) {
      int s0 = s_src[k], s1 = s_src[k + 1], s2 = s_src[k + 2], s3 = s_src[k + 3];
      float c0 = s_coef[k][w], c1 = s_coef[k + 1][w];
      float c2 = s_coef[k + 2][w], c3 = s_coef[k + 3][w];
      float f0 = feat[(size_t)s0 * 256 + tid];
      float f1 = feat[(size_t)s1 * 256 + tid];
      float f2 = feat[(size_t)s2 * 256 + tid];
      float f3 = feat[(size_t)s3 * 256 + tid];
      acc = fmaf(c0 * invd, f0, acc);
      acc = fmaf(c1 * invd, f1, acc);
      acc = fmaf(c2 * invd, f2, acc);
      acc = fmaf(c3 * invd, f3, acc);
    }
    for (; k < cnt; ++k)
      acc = fmaf(s_coef[k][w] * invd, feat[(size_t)s_src[k] * 256 + tid], acc);
  }
  gat[(size_t)n * 256 + tid] = acc + bias[tid];
}

// ============== enhance: top5/bot2 select, pool, t/bo (rank-8 MLPs) ==============
__global__ __launch_bounds__(256)
void enhance_pool_kernel(const int* __restrict__ nbr_idx, const float* __restrict__ nbr_w,
                         const float* __restrict__ gat,
                         const float* __restrict__ Wt, const float* __restrict__ bt,
                         const float* __restrict__ Wb, const float* __restrict__ bb,
                         float* __restrict__ tvec, float* __restrict__ bvec, int n_nodes)
{
  int n = blockIdx.x;
  int tid = threadIdx.x;
  __shared__ float sw[16];
  __shared__ int sidx[16];
  __shared__ int stop[5];
  __shared__ int sbot[2];
  __shared__ float m5[256];
  __shared__ float m2[256];
  if (tid < 16) {
    sw[tid] = nbr_w[(size_t)n * 16 + tid];
    sidx[tid] = nbr_idx[(size_t)n * 16 + tid];
  }
  __syncthreads();
  if (tid < 16) {
    float wj = sw[tid];
    int rhi = 0, rlo = 0;
    for (int i = 0; i < 16; ++i) {
      float wi = sw[i];
      if (wi > wj || (wi == wj && i < tid)) rhi++;
      if (wi < wj || (wi == wj && i < tid)) rlo++;
    }
    if (rhi < 5) stop[rhi] = sidx[tid];
    if (rlo < 2) sbot[rlo] = sidx[tid];
  }
  __syncthreads();
  float s5 = 0.f;
#pragma unroll
  for (int q = 0; q < 5; ++q) s5 += gat[(size_t)stop[q] * 256 + tid];
  float s2 = gat[(size_t)sbot[0] * 256 + tid] + gat[(size_t)sbot[1] * 256 + tid];
  m5[tid] = s5 / 5.0f;
  m2[tid] = s2 * 0.5f;
  __syncthreads();
  int wid = tid >> 6, lane = tid & 63;
#pragma unroll
  for (int o = 0; o < 4; ++o) {
    int j = wid * 4 + o;          // 0..15: 0-7 -> t, 8-15 -> bo
    bool isT = (j < 8);
    int jj = isT ? j : (j - 8);
    const float* M = isT ? m5 : m2;
    const float* Wm = isT ? Wt : Wb;
    float p = 0.f;
#pragma unroll
    for (int r = 0; r < 4; ++r) {
      int c = lane + r * 64;
      p = fmaf(M[c], Wm[(size_t)c * 8 + jj], p);
    }
#pragma unroll
    for (int o2 = 32; o2 >= 1; o2 >>= 1) p += __shfl_xor(p, o2, 64);
    if (lane == 0) {
      if (isT) tvec[(size_t)n * 8 + jj] = p + bt[jj];
      else     bvec[(size_t)n * 8 + jj] = p + bb[jj];
    }
  }
}

extern "C" void kernel_launch(void* const* d_in, const int* in_sizes, int n_in,
                              void* d_out, int out_size, void* d_ws, size_t ws_size,
                              hipStream_t stream)
{
  const int N_ = N_NODES;
  const int E_ = N_EDGES;

  const float* h = (const float*)d_in[0];
  const float* Wt = (const float*)d_in[28];
  const float* bt = (const float*)d_in[29];
  const float* Wb = (const float*)d_in[30];
  const float* bb = (const float*)d_in[31];
  const float* Wp = (const float*)d_in[32];
  const float* bp = (const float*)d_in[33];
  float* out = (float*)d_out;

  // workspace carve-up (256B aligned)
  char* wsb = (char*)d_ws;
  size_t o = 0;
  auto alloc = [&](size_t bytes) -> void* {
    void* p = wsb + o;
    o = (o + bytes + 255) & ~(size_t)255;
    return p;
  };
  float* feat   = (float*)alloc((size_t)N_ * 256 * 4);
  float* gat    = (float*)alloc((size_t)N_ * 256 * 4);
  float* a_un   = (float*)alloc((size_t)E_ * 4 * 4);
  float* el     = (float*)alloc((size_t)N_ * 4 * 4);
  float* er     = (float*)alloc((size_t)N_ * 4 * 4);
  float* denom  = (float*)alloc((size_t)N_ * 4 * 4);
  float* tvec   = (float*)alloc((size_t)N_ * 8 * 4);
  float* bvec   = (float*)alloc((size_t)N_ * 8 * 4);
  int*   off    = (int*)alloc((size_t)(N_ + 1) * 4);
  int*   cursor = (int*)alloc((size_t)N_ * 4);
  int*   eid    = (int*)alloc((size_t)E_ * 4);
  (void)ws_size; (void)in_sizes; (void)n_in; (void)out_size;

  const int row_blocks = (N_ + 63) / 64;   // 469
  const int edge_blocks = (E_ + 255) / 256; // 1875

  for (int et = 0; et < 3; ++et) {
    const int base = 1 + et * 9;
    const int* src = (const int*)d_in[base + 0];
    const int* dst = (const int*)d_in[base + 1];
    const float* ew = (const float*)d_in[base + 2];
    const int* nbr_idx = (const int*)d_in[base + 3];
    const float* nbr_w = (const float*)d_in[base + 4];
    const float* W = (const float*)d_in[base + 5];
    const float* al = (const float*)d_in[base + 6];
    const float* ar = (const float*)d_in[base + 7];
    const float* b = (const float*)d_in[base + 8];

    hipMemsetAsync(denom, 0, (size_t)N_ * 4 * sizeof(float), stream);
    hipMemsetAsync(cursor, 0, (size_t)N_ * sizeof(int), stream);

    gemm_kernel<0><<<dim3(row_blocks, 4), 256, 0, stream>>>(
        h, W, feat, N_, al, ar, el, er,
        nullptr, nullptr, nullptr, nullptr, nullptr, 256, 0);

    edge_pass_kernel<<<edge_blocks, 256, 0, stream>>>(
        src, dst, ew, el, er, a_un, denom, cursor, E_);

    scan_kernel<<<1, 1024, 0, stream>>>(cursor, off, N_, E_);

    fill_kernel<<<edge_blocks, 256, 0, stream>>>(dst, cursor, eid, E_);

    aggregate_kernel<<<N_, 256, 0, stream>>>(
        off, eid, src, a_un, denom, feat, b, gat, N_);

    enhance_pool_kernel<<<N_, 256, 0, stream>>>(
        nbr_idx, nbr_w, gat, Wt, bt, Wb, bb, tvec, bvec, N_);

    gemm_kernel<1><<<dim3(row_blocks, 4), 256, 0, stream>>>(
        gat, Wp, out, N_, nullptr, nullptr, nullptr, nullptr,
        tvec, bvec, Wp + 256 * 256, Wp + 264 * 256, bp, 768, et * 256);
  }
}

// Round 2
// 1313.017 us; speedup vs baseline: 1.4522x; 1.4522x over previous
//
#include <hip/hip_runtime.h>
#include <hip/hip_fp16.h>

#define N_NODES 30000
#define N_EDGES 480000

// ================= GEMM 64x64 tile, f32 math, K=256 =================
// MODE 0: feat(f16) = h(f32)@W; epilogue computes el/er (col-tile == head, DH=64)
// MODE 1: out(f32) = gat(f16)@Wp0 + t@Wp1 + bo@Wp2 + bp, strided store into d_out
template<int MODE>
__global__ __launch_bounds__(256)
void gemm_kernel(const float* __restrict__ Af, const __half* __restrict__ Ah,
                 const float* __restrict__ B,
                 float* __restrict__ Cf, __half* __restrict__ Ch, int M,
                 const float* __restrict__ al, const float* __restrict__ ar,
                 float* __restrict__ el, float* __restrict__ er,
                 const float* __restrict__ tvec, const float* __restrict__ bvec,
                 const float* __restrict__ Wp1, const float* __restrict__ Wp2,
                 const float* __restrict__ bp, int ldc, int coff)
{
  __shared__ float As[16][65];
  __shared__ float Bs[16][64];
  __shared__ float W1s[8][64];
  __shared__ float W2s[8][64];

  const int tid = threadIdx.x;
  const int tx = tid & 15, ty = tid >> 4;
  const int bm = blockIdx.x * 64;
  const int ct = blockIdx.y;      // col tile == head (MODE 0)
  const int bn = ct * 64;

  if (MODE == 1) {
    if (tid < 128) {
      int r = tid >> 4, c4 = (tid & 15) * 4;
      *(float4*)&W1s[r][c4] = *(const float4*)&Wp1[r * 256 + bn + c4];
    } else {
      int t2 = tid - 128;
      int r = t2 >> 4, c4 = (t2 & 15) * 4;
      *(float4*)&W2s[r][c4] = *(const float4*)&Wp2[r * 256 + bn + c4];
    }
  }

  const int arow = tid >> 2, acol = (tid & 3) * 4;
  const int brow = tid >> 4, bcol = (tid & 15) * 4;
  const bool arow_ok = (bm + arow) < M;
  const float* Aptr_f = (MODE == 0) ? (Af + (size_t)(bm + arow) * 256 + acol) : nullptr;
  const __half* Aptr_h = (MODE == 1) ? (Ah + (size_t)(bm + arow) * 256 + acol) : nullptr;
  const float* Bptr = B + (size_t)brow * 256 + bn + bcol;

  float acc[4][4] = {};

  for (int k0 = 0; k0 < 256; k0 += 16) {
    float a0 = 0.f, a1 = 0.f, a2 = 0.f, a3 = 0.f;
    if (arow_ok) {
      if (MODE == 0) {
        float4 av = *(const float4*)(Aptr_f + k0);
        a0 = av.x; a1 = av.y; a2 = av.z; a3 = av.w;
      } else {
        uint2 u = *(const uint2*)(Aptr_h + k0);
        float2 f01 = __half22float2(*(__half2*)&u.x);
        float2 f23 = __half22float2(*(__half2*)&u.y);
        a0 = f01.x; a1 = f01.y; a2 = f23.x; a3 = f23.y;
      }
    }
    float4 bv = *(const float4*)(Bptr + (size_t)k0 * 256);
    __syncthreads();
    As[acol + 0][arow] = a0;
    As[acol + 1][arow] = a1;
    As[acol + 2][arow] = a2;
    As[acol + 3][arow] = a3;
    *(float4*)&Bs[brow][bcol] = bv;
    __syncthreads();
#pragma unroll
    for (int kk = 0; kk < 16; ++kk) {
      float4 b4 = *(const float4*)&Bs[kk][tx * 4];
      float bb4[4] = {b4.x, b4.y, b4.z, b4.w};
#pragma unroll
      for (int i = 0; i < 4; ++i) {
        float a = As[kk][ty * 4 + i];
#pragma unroll
        for (int j = 0; j < 4; ++j) acc[i][j] = fmaf(a, bb4[j], acc[i][j]);
      }
    }
  }

  if (MODE == 0) {
    float alv[4], arv[4];
#pragma unroll
    for (int j = 0; j < 4; ++j) {
      alv[j] = al[bn + tx * 4 + j];
      arv[j] = ar[bn + tx * 4 + j];
    }
#pragma unroll
    for (int i = 0; i < 4; ++i) {
      int row = bm + ty * 4 + i;
      float pe = 0.f, pr = 0.f;
#pragma unroll
      for (int j = 0; j < 4; ++j) {
        pe = fmaf(acc[i][j], alv[j], pe);
        pr = fmaf(acc[i][j], arv[j], pr);
      }
#pragma unroll
      for (int o = 8; o >= 1; o >>= 1) {
        pe += __shfl_xor(pe, o, 64);
        pr += __shfl_xor(pr, o, 64);
      }
      if (row < M) {
        if (tx == 0) {
          el[row * 4 + ct] = pe;
          er[row * 4 + ct] = pr;
        }
        __half2 h01 = __floats2half2_rn(acc[i][0], acc[i][1]);
        __half2 h23 = __floats2half2_rn(acc[i][2], acc[i][3]);
        uint2 st;
        st.x = *(unsigned int*)&h01;
        st.y = *(unsigned int*)&h23;
        *(uint2*)&Ch[(size_t)row * 256 + bn + tx * 4] = st;
      }
    }
  } else {
    float bpv[4];
#pragma unroll
    for (int j = 0; j < 4; ++j) bpv[j] = bp[bn + tx * 4 + j];
#pragma unroll
    for (int i = 0; i < 4; ++i) {
      int row = bm + ty * 4 + i;
      if (row >= M) continue;
      float4 tlo = *(const float4*)&tvec[(size_t)row * 8];
      float4 thi = *(const float4*)&tvec[(size_t)row * 8 + 4];
      float4 blo = *(const float4*)&bvec[(size_t)row * 8];
      float4 bhi = *(const float4*)&bvec[(size_t)row * 8 + 4];
      float tv8[8] = {tlo.x, tlo.y, tlo.z, tlo.w, thi.x, thi.y, thi.z, thi.w};
      float bv8[8] = {blo.x, blo.y, blo.z, blo.w, bhi.x, bhi.y, bhi.z, bhi.w};
      float outv[4];
#pragma unroll
      for (int j = 0; j < 4; ++j) {
        float v = acc[i][j] + bpv[j];
        int c = tx * 4 + j;
#pragma unroll
        for (int k = 0; k < 8; ++k) {
          v = fmaf(tv8[k], W1s[k][c], v);
          v = fmaf(bv8[k], W2s[k][c], v);
        }
        outv[j] = v;
      }
      *(float4*)&Cf[(size_t)row * ldc + coff + bn + tx * 4] =
          make_float4(outv[0], outv[1], outv[2], outv[3]);
    }
  }
}

// ============== per-edge: exp(leakyrelu(el[s]+er[d])), denom+count atomics ==============
__global__ void edge_pass_kernel(const int* __restrict__ src, const int* __restrict__ dst,
                                 const float* __restrict__ ew, const float* __restrict__ el,
                                 const float* __restrict__ er, float* __restrict__ a_un,
                                 float* denom, int* counts, int ne)
{
  int e = blockIdx.x * 256 + threadIdx.x;
  if (e >= ne) return;
  int s = src[e], d = dst[e];
  float w = ew[e];
  float4 l4 = *(const float4*)&el[(size_t)s * 4];
  float4 r4 = *(const float4*)&er[(size_t)d * 4];
  float v0 = l4.x + r4.x; v0 = v0 > 0.f ? v0 : 0.2f * v0;
  float v1 = l4.y + r4.y; v1 = v1 > 0.f ? v1 : 0.2f * v1;
  float v2 = l4.z + r4.z; v2 = v2 > 0.f ? v2 : 0.2f * v2;
  float v3 = l4.w + r4.w; v3 = v3 > 0.f ? v3 : 0.2f * v3;
  float x0 = __expf(v0), x1 = __expf(v1), x2 = __expf(v2), x3 = __expf(v3);
  *(float4*)&a_un[(size_t)e * 4] = make_float4(x0 * w, x1 * w, x2 * w, x3 * w);
  atomicAdd(&denom[d * 4 + 0], x0);
  atomicAdd(&denom[d * 4 + 1], x1);
  atomicAdd(&denom[d * 4 + 2], x2);
  atomicAdd(&denom[d * 4 + 3], x3);
  atomicAdd(&counts[d], 1);
}

// ============== single-block scan over counts -> offsets + cursor (in place) ==============
__global__ __launch_bounds__(1024)
void scan_kernel(int* __restrict__ cc, int* __restrict__ off, int n, int total)
{
  __shared__ int wsum[16];
  __shared__ int woff[16];
  __shared__ int s_carry, s_chunk;
  int tid = threadIdx.x;
  int lane = tid & 63, wid = tid >> 6;
  if (tid == 0) s_carry = 0;
  __syncthreads();
  for (int base = 0; base < n; base += 1024) {
    int i = base + tid;
    int v = (i < n) ? cc[i] : 0;
    int x = v;
#pragma unroll
    for (int s = 1; s < 64; s <<= 1) {
      int y = __shfl_up(x, s, 64);
      if (lane >= s) x += y;
    }
    if (lane == 63) wsum[wid] = x;
    __syncthreads();
    if (wid == 0 && lane < 16) {
      int ws_ = wsum[lane];
      int xx = ws_;
#pragma unroll
      for (int s = 1; s < 16; s <<= 1) {
        int y = __shfl_up(xx, s, 64);
        if (lane >= s) xx += y;
      }
      woff[lane] = xx - ws_;
      if (lane == 15) s_chunk = xx;
    }
    __syncthreads();
    int excl = s_carry + woff[wid] + (x - v);
    if (i < n) { off[i] = excl; cc[i] = excl; }
    __syncthreads();
    if (tid == 0) s_carry += s_chunk;
    __syncthreads();
  }
  if (tid == 0) off[n] = total;
}

// ============== CSR fill ==============
__global__ void fill_kernel(const int* __restrict__ dst, int* cursor,
                            int* __restrict__ eid, int ne)
{
  int e = blockIdx.x * 256 + threadIdx.x;
  if (e >= ne) return;
  int p = atomicAdd(&cursor[dst[e]], 1);
  eid[p] = e;
}

// ============== per-dst aggregation: gat[n] = sum a*feat[src] + b (f16 feat/gat) ==============
__global__ __launch_bounds__(256)
void aggregate_kernel(const int* __restrict__ off, const int* __restrict__ eid,
                      const int* __restrict__ src, const float* __restrict__ a_un,
                      const float* __restrict__ denom, const __half* __restrict__ feat,
                      const float* __restrict__ bias, __half* __restrict__ gat, int n_nodes)
{
  int n = blockIdx.x;
  int tid = threadIdx.x;
  int lane = tid & 63, wv = tid >> 6;
  int hd = lane >> 4;                    // head of this lane's 4-column slice
  __shared__ int s_src[256];
  __shared__ float s_coef[256][4];
  __shared__ float red[4][256];
  int e0 = off[n], e1 = off[n + 1];
  float dn = denom[(size_t)n * 4 + hd];
  float invd = (dn != 0.f) ? 1.f / dn : 0.f;
  float ac0 = 0.f, ac1 = 0.f, ac2 = 0.f, ac3 = 0.f;

  for (int base = e0; base < e1; base += 256) {
    int cnt = min(256, e1 - base);
    __syncthreads();
    if (tid < cnt) {
      int e = eid[base + tid];
      s_src[tid] = src[e];
      float4 au = *(const float4*)&a_un[(size_t)e * 4];
      s_coef[tid][0] = au.x; s_coef[tid][1] = au.y;
      s_coef[tid][2] = au.z; s_coef[tid][3] = au.w;
    }
    __syncthreads();
    int k = wv;
    for (; k + 12 < cnt; k += 16) {
      int sA = s_src[k], sB = s_src[k + 4], sC = s_src[k + 8], sD = s_src[k + 12];
      float cA = s_coef[k][hd] * invd;
      float cB = s_coef[k + 4][hd] * invd;
      float cC = s_coef[k + 8][hd] * invd;
      float cD = s_coef[k + 12][hd] * invd;
      uint2 uA = *(const uint2*)(feat + (size_t)sA * 256 + lane * 4);
      uint2 uB = *(const uint2*)(feat + (size_t)sB * 256 + lane * 4);
      uint2 uC = *(const uint2*)(feat + (size_t)sC * 256 + lane * 4);
      uint2 uD = *(const uint2*)(feat + (size_t)sD * 256 + lane * 4);
      float2 A01 = __half22float2(*(__half2*)&uA.x), A23 = __half22float2(*(__half2*)&uA.y);
      float2 B01 = __half22float2(*(__half2*)&uB.x), B23 = __half22float2(*(__half2*)&uB.y);
      float2 C01 = __half22float2(*(__half2*)&uC.x), C23 = __half22float2(*(__half2*)&uC.y);
      float2 D01 = __half22float2(*(__half2*)&uD.x), D23 = __half22float2(*(__half2*)&uD.y);
      ac0 = fmaf(cA, A01.x, ac0); ac1 = fmaf(cA, A01.y, ac1);
      ac2 = fmaf(cA, A23.x, ac2); ac3 = fmaf(cA, A23.y, ac3);
      ac0 = fmaf(cB, B01.x, ac0); ac1 = fmaf(cB, B01.y, ac1);
      ac2 = fmaf(cB, B23.x, ac2); ac3 = fmaf(cB, B23.y, ac3);
      ac0 = fmaf(cC, C01.x, ac0); ac1 = fmaf(cC, C01.y, ac1);
      ac2 = fmaf(cC, C23.x, ac2); ac3 = fmaf(cC, C23.y, ac3);
      ac0 = fmaf(cD, D01.x, ac0); ac1 = fmaf(cD, D01.y, ac1);
      ac2 = fmaf(cD, D23.x, ac2); ac3 = fmaf(cD, D23.y, ac3);
    }
    for (; k < cnt; k += 4) {
      int s0 = s_src[k];
      float c0 = s_coef[k][hd] * invd;
      uint2 u = *(const uint2*)(feat + (size_t)s0 * 256 + lane * 4);
      float2 f01 = __half22float2(*(__half2*)&u.x), f23 = __half22float2(*(__half2*)&u.y);
      ac0 = fmaf(c0, f01.x, ac0); ac1 = fmaf(c0, f01.y, ac1);
      ac2 = fmaf(c0, f23.x, ac2); ac3 = fmaf(c0, f23.y, ac3);
    }
  }
  red[wv][lane * 4 + 0] = ac0;
  red[wv][lane * 4 + 1] = ac1;
  red[wv][lane * 4 + 2] = ac2;
  red[wv][lane * 4 + 3] = ac3;
  __syncthreads();
  float v = red[0][tid] + red[1][tid] + red[2][tid] + red[3][tid] + bias[tid];
  gat[(size_t)n * 256 + tid] = __float2half_rn(v);
}

// ============== enhance: wave-per-node, barrier-free; top5/bot2 select, pool, rank-8 MLPs ==============
__global__ __launch_bounds__(256)
void enhance_pool_kernel(const int* __restrict__ nbr_idx, const float* __restrict__ nbr_w,
                         const __half* __restrict__ gat,
                         const float* __restrict__ Wt, const float* __restrict__ bt,
                         const float* __restrict__ Wb, const float* __restrict__ bb,
                         float* __restrict__ tvec, float* __restrict__ bvec, int n_nodes)
{
  int wave = (blockIdx.x * 256 + threadIdx.x) >> 6;   // one node per wave
  int lane = threadIdx.x & 63;
  if (wave >= n_nodes) return;
  const int n = wave;
  const int l16 = lane & 15;

  float w = nbr_w[(size_t)n * 16 + l16];
  int idx = nbr_idx[(size_t)n * 16 + l16];

  // rank of element l16 among the 16 weights (strict tie-break: lower index wins)
  int rhi = 0, rlo = 0;
#pragma unroll
  for (int i = 0; i < 16; ++i) {
    float wi = __shfl(w, i, 64);
    rhi += (wi > w) || (wi == w && i < l16);
    rlo += (wi < w) || (wi == w && i < l16);
  }

  int rows[7];
#pragma unroll
  for (int q = 0; q < 5; ++q) {
    unsigned long long m = __ballot(lane < 16 && rhi == q);
    rows[q] = __shfl(idx, __ffsll(m) - 1, 64);
  }
#pragma unroll
  for (int q = 0; q < 2; ++q) {
    unsigned long long m = __ballot(lane < 16 && rlo == q);
    rows[5 + q] = __shfl(idx, __ffsll(m) - 1, 64);
  }

  // 7 independent 8B f16 gathers; lane covers columns lane*4 .. lane*4+3
  float s5[4] = {0.f, 0.f, 0.f, 0.f};
  float s2[4] = {0.f, 0.f, 0.f, 0.f};
#pragma unroll
  for (int q = 0; q < 7; ++q) {
    uint2 u = *(const uint2*)(gat + (size_t)rows[q] * 256 + lane * 4);
    float2 f01 = __half22float2(*(__half2*)&u.x);
    float2 f23 = __half22float2(*(__half2*)&u.y);
    if (q < 5) {
      s5[0] += f01.x; s5[1] += f01.y; s5[2] += f23.x; s5[3] += f23.y;
    } else {
      s2[0] += f01.x; s2[1] += f01.y; s2[2] += f23.x; s2[3] += f23.y;
    }
  }
  float m5[4], m2[4];
#pragma unroll
  for (int r = 0; r < 4; ++r) { m5[r] = s5[r] * 0.2f; m2[r] = s2[r] * 0.5f; }

  // rank-8 MLPs: p[0..7] = t partials, p[8..15] = bo partials
  float p[16];
#pragma unroll
  for (int j = 0; j < 16; ++j) p[j] = 0.f;
#pragma unroll
  for (int r = 0; r < 4; ++r) {
    int c = lane * 4 + r;
    const float* wtr = &Wt[(size_t)c * 8];
    const float* wbr = &Wb[(size_t)c * 8];
#pragma unroll
    for (int j = 0; j < 8; ++j) {
      p[j]     = fmaf(m5[r], wtr[j], p[j]);
      p[8 + j] = fmaf(m2[r], wbr[j], p[8 + j]);
    }
  }
#pragma unroll
  for (int o = 32; o >= 1; o >>= 1) {
#pragma unroll
    for (int j = 0; j < 16; ++j) p[j] += __shfl_xor(p[j], o, 64);
  }
  if (lane == 0) {
#pragma unroll
    for (int j = 0; j < 8; ++j) {
      tvec[(size_t)n * 8 + j] = p[j] + bt[j];
      bvec[(size_t)n * 8 + j] = p[8 + j] + bb[j];
    }
  }
}

extern "C" void kernel_launch(void* const* d_in, const int* in_sizes, int n_in,
                              void* d_out, int out_size, void* d_ws, size_t ws_size,
                              hipStream_t stream)
{
  const int N_ = N_NODES;
  const int E_ = N_EDGES;

  const float* h = (const float*)d_in[0];
  const float* Wt = (const float*)d_in[28];
  const float* bt = (const float*)d_in[29];
  const float* Wb = (const float*)d_in[30];
  const float* bb = (const float*)d_in[31];
  const float* Wp = (const float*)d_in[32];
  const float* bp = (const float*)d_in[33];
  float* out = (float*)d_out;

  // workspace carve-up (256B aligned)
  char* wsb = (char*)d_ws;
  size_t o = 0;
  auto alloc = [&](size_t bytes) -> void* {
    void* p = wsb + o;
    o = (o + bytes + 255) & ~(size_t)255;
    return p;
  };
  __half* feat  = (__half*)alloc((size_t)N_ * 256 * 2);
  __half* gat   = (__half*)alloc((size_t)N_ * 256 * 2);
  float* a_un   = (float*)alloc((size_t)E_ * 4 * 4);
  float* el     = (float*)alloc((size_t)N_ * 4 * 4);
  float* er     = (float*)alloc((size_t)N_ * 4 * 4);
  float* denom  = (float*)alloc((size_t)N_ * 4 * 4);
  float* tvec   = (float*)alloc((size_t)N_ * 8 * 4);
  float* bvec   = (float*)alloc((size_t)N_ * 8 * 4);
  int*   off    = (int*)alloc((size_t)(N_ + 1) * 4);
  int*   cursor = (int*)alloc((size_t)N_ * 4);
  int*   eid    = (int*)alloc((size_t)E_ * 4);
  (void)ws_size; (void)in_sizes; (void)n_in; (void)out_size;

  const int row_blocks = (N_ + 63) / 64;    // 469
  const int edge_blocks = (E_ + 255) / 256; // 1875
  const int wave_blocks = (N_ + 3) / 4;     // 7500 (4 node-waves per block)

  for (int et = 0; et < 3; ++et) {
    const int base = 1 + et * 9;
    const int* src = (const int*)d_in[base + 0];
    const int* dst = (const int*)d_in[base + 1];
    const float* ew = (const float*)d_in[base + 2];
    const int* nbr_idx = (const int*)d_in[base + 3];
    const float* nbr_w = (const float*)d_in[base + 4];
    const float* W = (const float*)d_in[base + 5];
    const float* al = (const float*)d_in[base + 6];
    const float* ar = (const float*)d_in[base + 7];
    const float* b = (const float*)d_in[base + 8];

    hipMemsetAsync(denom, 0, (size_t)N_ * 4 * sizeof(float), stream);
    hipMemsetAsync(cursor, 0, (size_t)N_ * sizeof(int), stream);

    gemm_kernel<0><<<dim3(row_blocks, 4), 256, 0, stream>>>(
        h, nullptr, W, nullptr, feat, N_, al, ar, el, er,
        nullptr, nullptr, nullptr, nullptr, nullptr, 256, 0);

    edge_pass_kernel<<<edge_blocks, 256, 0, stream>>>(
        src, dst, ew, el, er, a_un, denom, cursor, E_);

    scan_kernel<<<1, 1024, 0, stream>>>(cursor, off, N_, E_);

    fill_kernel<<<edge_blocks, 256, 0, stream>>>(dst, cursor, eid, E_);

    aggregate_kernel<<<N_, 256, 0, stream>>>(
        off, eid, src, a_un, denom, feat, b, gat, N_);

    enhance_pool_kernel<<<wave_blocks, 256, 0, stream>>>(
        nbr_idx, nbr_w, gat, Wt, bt, Wb, bb, tvec, bvec, N_);

    gemm_kernel<1><<<dim3(row_blocks, 4), 256, 0, stream>>>(
        nullptr, gat, Wp, out, nullptr, N_, nullptr, nullptr, nullptr, nullptr,
        tvec, bvec, Wp + 256 * 256, Wp + 264 * 256, bp, 768, et * 256);
  }
}

// Round 3
// 759.028 us; speedup vs baseline: 2.5120x; 1.7299x over previous
//
#include <hip/hip_runtime.h>
#include <hip/hip_fp16.h>

#define N_NODES 30000
#define N_EDGES 480000

typedef _Float16 f16;
typedef f16 f16x8 __attribute__((ext_vector_type(8)));
typedef float f32x4 __attribute__((ext_vector_type(4)));

// ================= one-time converts =================
__global__ void convert_h_kernel(const float* __restrict__ in, f16* __restrict__ out, int n8)
{
  int i = blockIdx.x * 256 + threadIdx.x;
  if (i >= n8) return;
  float4 a = *(const float4*)(in + (size_t)i * 8);
  float4 b = *(const float4*)(in + (size_t)i * 8 + 4);
  f16x8 v;
  v[0] = (f16)a.x; v[1] = (f16)a.y; v[2] = (f16)a.z; v[3] = (f16)a.w;
  v[4] = (f16)b.x; v[5] = (f16)b.y; v[6] = (f16)b.z; v[7] = (f16)b.w;
  *(f16x8*)(out + (size_t)i * 8) = v;
}

// out[n][k] = (f16) in[k][n], 256x256
__global__ void transpose_w_kernel(const float* __restrict__ in, f16* __restrict__ out)
{
  int t = blockIdx.x * 256 + threadIdx.x;   // 65536
  int n = t >> 8, k = t & 255;
  out[t] = (f16)in[k * 256 + n];
}

// ================= MFMA GEMM: 64x64 tile, f16 in, f32 acc =================
// MODE 0: feat(f16) = A@B; epilogue el/er (col-tile == head)
// MODE 1: out(f32) = A@B + t@Wp1 + bo@Wp2 + bp, strided store
template<int MODE>
__global__ __launch_bounds__(256)
void gemm_mfma(const f16* __restrict__ A, const f16* __restrict__ BT,
               f16* __restrict__ Ch, float* __restrict__ Cf, int M,
               const float* __restrict__ al, const float* __restrict__ ar,
               float* __restrict__ el, float* __restrict__ er,
               const float* __restrict__ tvec, const float* __restrict__ bvec,
               const float* __restrict__ Wp1, const float* __restrict__ Wp2,
               const float* __restrict__ bp, int ldc, int coff)
{
  __shared__ alignas(16) f16 As[64][40];
  __shared__ alignas(16) f16 Bs[64][40];
  __shared__ float W1s[8][64];
  __shared__ float W2s[8][64];
  __shared__ float t_lds[64][8];
  __shared__ float b_lds[64][8];

  const int tid = threadIdx.x;
  const int lane = tid & 63, wv = tid >> 6;
  const int l15 = lane & 15, lq = lane >> 4;
  const int bm = blockIdx.x * 64;
  const int ct = blockIdx.y;
  const int bn = ct * 64;

  if (MODE == 1) {
    if (tid < 128) {
      int r = tid >> 4, c4 = (tid & 15) * 4;
      *(float4*)&W1s[r][c4] = *(const float4*)&Wp1[r * 256 + bn + c4];
    } else {
      int t2 = tid - 128;
      int r = t2 >> 4, c4 = (t2 & 15) * 4;
      *(float4*)&W2s[r][c4] = *(const float4*)&Wp2[r * 256 + bn + c4];
    }
    {
      int r = tid >> 2, c = (tid & 3) * 2;
      int row = bm + r;
      float2 tv = make_float2(0.f, 0.f), bv2 = make_float2(0.f, 0.f);
      if (row < M) {
        tv  = *(const float2*)&tvec[(size_t)row * 8 + c];
        bv2 = *(const float2*)&bvec[(size_t)row * 8 + c];
      }
      t_lds[r][c] = tv.x;  t_lds[r][c + 1] = tv.y;
      b_lds[r][c] = bv2.x; b_lds[r][c + 1] = bv2.y;
    }
  }

  const int arow = tid >> 2, k8 = (tid & 3) * 8;
  const bool arow_ok = (bm + arow) < M;
  const f16* Aptr = A + (size_t)(bm + arow) * 256 + k8;
  const f16* Bptr = BT + (size_t)(bn + arow) * 256 + k8;

  f32x4 acc[4] = {};   // 4 N-frags of 16 cols each

  for (int k0 = 0; k0 < 256; k0 += 32) {
    uint4 av = make_uint4(0u, 0u, 0u, 0u);
    if (arow_ok) av = *(const uint4*)(Aptr + k0);
    uint4 bv = *(const uint4*)(Bptr + k0);
    __syncthreads();
    *(uint4*)&As[arow][k8] = av;
    *(uint4*)&Bs[arow][k8] = bv;
    __syncthreads();
    f16x8 af = *(const f16x8*)&As[wv * 16 + l15][lq * 8];
#pragma unroll
    for (int nf = 0; nf < 4; ++nf) {
      f16x8 bf = *(const f16x8*)&Bs[nf * 16 + l15][lq * 8];
      acc[nf] = __builtin_amdgcn_mfma_f32_16x16x32_f16(af, bf, acc[nf], 0, 0, 0);
    }
  }

  if (MODE == 0) {
    float alv[4], arv[4];
#pragma unroll
    for (int nf = 0; nf < 4; ++nf) {
      alv[nf] = al[bn + nf * 16 + l15];
      arv[nf] = ar[bn + nf * 16 + l15];
    }
#pragma unroll
    for (int i = 0; i < 4; ++i) {
      int row = bm + wv * 16 + lq * 4 + i;
      float pe = 0.f, pr = 0.f;
#pragma unroll
      for (int nf = 0; nf < 4; ++nf) {
        pe = fmaf(acc[nf][i], alv[nf], pe);
        pr = fmaf(acc[nf][i], arv[nf], pr);
      }
#pragma unroll
      for (int o = 8; o >= 1; o >>= 1) {
        pe += __shfl_xor(pe, o, 64);
        pr += __shfl_xor(pr, o, 64);
      }
      if (row < M) {
        if (l15 == 0) {
          el[row * 4 + ct] = pe;
          er[row * 4 + ct] = pr;
        }
#pragma unroll
        for (int nf = 0; nf < 4; ++nf)
          Ch[(size_t)row * 256 + bn + nf * 16 + l15] = (f16)acc[nf][i];
      }
    }
  } else {
    float bpv[4];
#pragma unroll
    for (int nf = 0; nf < 4; ++nf) bpv[nf] = bp[bn + nf * 16 + l15];
#pragma unroll
    for (int i = 0; i < 4; ++i) {
      int rl = wv * 16 + lq * 4 + i;
      int row = bm + rl;
      if (row >= M) continue;
#pragma unroll
      for (int nf = 0; nf < 4; ++nf) {
        int c = nf * 16 + l15;
        float v = acc[nf][i] + bpv[nf];
#pragma unroll
        for (int k = 0; k < 8; ++k) {
          v = fmaf(t_lds[rl][k], W1s[k][c], v);
          v = fmaf(b_lds[rl][k], W2s[k][c], v);
        }
        Cf[(size_t)row * ldc + coff + bn + c] = v;
      }
    }
  }
}

// ============== count edges per dst ==============
__global__ void count_kernel(const int* __restrict__ dst, int* cursor, int ne)
{
  int e = blockIdx.x * 256 + threadIdx.x;
  if (e < ne) atomicAdd(&cursor[dst[e]], 1);
}

// ============== single-block scan over counts -> offsets + cursor (in place) ==============
__global__ __launch_bounds__(1024)
void scan_kernel(int* __restrict__ cc, int* __restrict__ off, int n, int total)
{
  __shared__ int wsum[16];
  __shared__ int woff[16];
  __shared__ int s_carry, s_chunk;
  int tid = threadIdx.x;
  int lane = tid & 63, wid = tid >> 6;
  if (tid == 0) s_carry = 0;
  __syncthreads();
  for (int base = 0; base < n; base += 1024) {
    int i = base + tid;
    int v = (i < n) ? cc[i] : 0;
    int x = v;
#pragma unroll
    for (int s = 1; s < 64; s <<= 1) {
      int y = __shfl_up(x, s, 64);
      if (lane >= s) x += y;
    }
    if (lane == 63) wsum[wid] = x;
    __syncthreads();
    if (wid == 0 && lane < 16) {
      int ws_ = wsum[lane];
      int xx = ws_;
#pragma unroll
      for (int s = 1; s < 16; s <<= 1) {
        int y = __shfl_up(xx, s, 64);
        if (lane >= s) xx += y;
      }
      woff[lane] = xx - ws_;
      if (lane == 15) s_chunk = xx;
    }
    __syncthreads();
    int excl = s_carry + woff[wid] + (x - v);
    if (i < n) { off[i] = excl; cc[i] = excl; }
    __syncthreads();
    if (tid == 0) s_carry += s_chunk;
    __syncthreads();
  }
  if (tid == 0) off[n] = total;
}

// ============== CSR fill ==============
__global__ void fill_kernel(const int* __restrict__ dst, int* cursor,
                            int* __restrict__ eid, int ne)
{
  int e = blockIdx.x * 256 + threadIdx.x;
  if (e >= ne) return;
  int p = atomicAdd(&cursor[dst[e]], 1);
  eid[p] = e;
}

// ============== per-dst aggregation (computes softmax in-block, atomic-free) ==============
__global__ __launch_bounds__(256)
void aggregate_kernel(const int* __restrict__ off, const int* __restrict__ eid,
                      const int* __restrict__ src, const float* __restrict__ ew,
                      const float* __restrict__ el, const float* __restrict__ er,
                      const __half* __restrict__ feat, const float* __restrict__ bias,
                      __half* __restrict__ gat)
{
  int n = blockIdx.x;
  int tid = threadIdx.x;
  int lane = tid & 63, wv = tid >> 6;
  int hd = lane >> 4;                    // head of this lane's 4-column slice
  __shared__ int s_src[256];
  __shared__ float s_coef[256][4];       // ex * ew
  __shared__ float s_ex[256][4];         // ex (for denom)
  __shared__ float red[4][256];
  __shared__ float sdn[4];
  int e0 = off[n], e1 = off[n + 1];
  float4 er4 = *(const float4*)&er[(size_t)n * 4];
  if (tid < 4) sdn[tid] = 0.f;
  float ac0 = 0.f, ac1 = 0.f, ac2 = 0.f, ac3 = 0.f;

  for (int base = e0; base < e1; base += 256) {
    int cnt = min(256, e1 - base);
    __syncthreads();
    if (tid < cnt) {
      int e = eid[base + tid];
      int s = src[e];
      s_src[tid] = s;
      float w = ew[e];
      float4 l4 = *(const float4*)&el[(size_t)s * 4];
      float v0 = l4.x + er4.x; v0 = v0 > 0.f ? v0 : 0.2f * v0;
      float v1 = l4.y + er4.y; v1 = v1 > 0.f ? v1 : 0.2f * v1;
      float v2 = l4.z + er4.z; v2 = v2 > 0.f ? v2 : 0.2f * v2;
      float v3 = l4.w + er4.w; v3 = v3 > 0.f ? v3 : 0.2f * v3;
      float x0 = __expf(v0), x1 = __expf(v1), x2 = __expf(v2), x3 = __expf(v3);
      s_ex[tid][0] = x0; s_ex[tid][1] = x1; s_ex[tid][2] = x2; s_ex[tid][3] = x3;
      s_coef[tid][0] = x0 * w; s_coef[tid][1] = x1 * w;
      s_coef[tid][2] = x2 * w; s_coef[tid][3] = x3 * w;
    }
    __syncthreads();
    if (wv == 0) {
      // lane handles head lane&3, k-stride group lane>>2
      float p = 0.f;
      for (int k = lane >> 2; k < cnt; k += 16) p += s_ex[k][lane & 3];
      p += __shfl_xor(p, 4, 64);
      p += __shfl_xor(p, 8, 64);
      p += __shfl_xor(p, 16, 64);
      p += __shfl_xor(p, 32, 64);
      if (lane < 4) sdn[lane] += p;
    }
    int k = wv;
    for (; k + 12 < cnt; k += 16) {
      int sA = s_src[k], sB = s_src[k + 4], sC = s_src[k + 8], sD = s_src[k + 12];
      float cA = s_coef[k][hd];
      float cB = s_coef[k + 4][hd];
      float cC = s_coef[k + 8][hd];
      float cD = s_coef[k + 12][hd];
      uint2 uA = *(const uint2*)(feat + (size_t)sA * 256 + lane * 4);
      uint2 uB = *(const uint2*)(feat + (size_t)sB * 256 + lane * 4);
      uint2 uC = *(const uint2*)(feat + (size_t)sC * 256 + lane * 4);
      uint2 uD = *(const uint2*)(feat + (size_t)sD * 256 + lane * 4);
      float2 A01 = __half22float2(*(__half2*)&uA.x), A23 = __half22float2(*(__half2*)&uA.y);
      float2 B01 = __half22float2(*(__half2*)&uB.x), B23 = __half22float2(*(__half2*)&uB.y);
      float2 C01 = __half22float2(*(__half2*)&uC.x), C23 = __half22float2(*(__half2*)&uC.y);
      float2 D01 = __half22float2(*(__half2*)&uD.x), D23 = __half22float2(*(__half2*)&uD.y);
      ac0 = fmaf(cA, A01.x, ac0); ac1 = fmaf(cA, A01.y, ac1);
      ac2 = fmaf(cA, A23.x, ac2); ac3 = fmaf(cA, A23.y, ac3);
      ac0 = fmaf(cB, B01.x, ac0); ac1 = fmaf(cB, B01.y, ac1);
      ac2 = fmaf(cB, B23.x, ac2); ac3 = fmaf(cB, B23.y, ac3);
      ac0 = fmaf(cC, C01.x, ac0); ac1 = fmaf(cC, C01.y, ac1);
      ac2 = fmaf(cC, C23.x, ac2); ac3 = fmaf(cC, C23.y, ac3);
      ac0 = fmaf(cD, D01.x, ac0); ac1 = fmaf(cD, D01.y, ac1);
      ac2 = fmaf(cD, D23.x, ac2); ac3 = fmaf(cD, D23.y, ac3);
    }
    for (; k < cnt; k += 4) {
      int s0 = s_src[k];
      float c0 = s_coef[k][hd];
      uint2 u = *(const uint2*)(feat + (size_t)s0 * 256 + lane * 4);
      float2 f01 = __half22float2(*(__half2*)&u.x), f23 = __half22float2(*(__half2*)&u.y);
      ac0 = fmaf(c0, f01.x, ac0); ac1 = fmaf(c0, f01.y, ac1);
      ac2 = fmaf(c0, f23.x, ac2); ac3 = fmaf(c0, f23.y, ac3);
    }
  }
  red[wv][lane * 4 + 0] = ac0;
  red[wv][lane * 4 + 1] = ac1;
  red[wv][lane * 4 + 2] = ac2;
  red[wv][lane * 4 + 3] = ac3;
  __syncthreads();
  float dn = sdn[tid >> 6];
  float invd = (dn != 0.f) ? 1.f / dn : 0.f;
  float v = (red[0][tid] + red[1][tid] + red[2][tid] + red[3][tid]) * invd + bias[tid];
  gat[(size_t)n * 256 + tid] = __float2half_rn(v);
}

// ============== enhance: wave-per-node, barrier-free ==============
__global__ __launch_bounds__(256)
void enhance_pool_kernel(const int* __restrict__ nbr_idx, const float* __restrict__ nbr_w,
                         const __half* __restrict__ gat,
                         const float* __restrict__ Wt, const float* __restrict__ bt,
                         const float* __restrict__ Wb, const float* __restrict__ bb,
                         float* __restrict__ tvec, float* __restrict__ bvec, int n_nodes)
{
  int wave = (blockIdx.x * 256 + threadIdx.x) >> 6;   // one node per wave
  int lane = threadIdx.x & 63;
  if (wave >= n_nodes) return;
  const int n = wave;
  const int l16 = lane & 15;

  float w = nbr_w[(size_t)n * 16 + l16];
  int idx = nbr_idx[(size_t)n * 16 + l16];

  int rhi = 0, rlo = 0;
#pragma unroll
  for (int i = 0; i < 16; ++i) {
    float wi = __shfl(w, i, 64);
    rhi += (wi > w) || (wi == w && i < l16);
    rlo += (wi < w) || (wi == w && i < l16);
  }

  int rows[7];
#pragma unroll
  for (int q = 0; q < 5; ++q) {
    unsigned long long m = __ballot(lane < 16 && rhi == q);
    rows[q] = __shfl(idx, __ffsll(m) - 1, 64);
  }
#pragma unroll
  for (int q = 0; q < 2; ++q) {
    unsigned long long m = __ballot(lane < 16 && rlo == q);
    rows[5 + q] = __shfl(idx, __ffsll(m) - 1, 64);
  }

  float s5[4] = {0.f, 0.f, 0.f, 0.f};
  float s2[4] = {0.f, 0.f, 0.f, 0.f};
#pragma unroll
  for (int q = 0; q < 7; ++q) {
    uint2 u = *(const uint2*)(gat + (size_t)rows[q] * 256 + lane * 4);
    float2 f01 = __half22float2(*(__half2*)&u.x);
    float2 f23 = __half22float2(*(__half2*)&u.y);
    if (q < 5) {
      s5[0] += f01.x; s5[1] += f01.y; s5[2] += f23.x; s5[3] += f23.y;
    } else {
      s2[0] += f01.x; s2[1] += f01.y; s2[2] += f23.x; s2[3] += f23.y;
    }
  }
  float m5[4], m2[4];
#pragma unroll
  for (int r = 0; r < 4; ++r) { m5[r] = s5[r] * 0.2f; m2[r] = s2[r] * 0.5f; }

  float p[16];
#pragma unroll
  for (int j = 0; j < 16; ++j) p[j] = 0.f;
#pragma unroll
  for (int r = 0; r < 4; ++r) {
    int c = lane * 4 + r;
    const float* wtr = &Wt[(size_t)c * 8];
    const float* wbr = &Wb[(size_t)c * 8];
#pragma unroll
    for (int j = 0; j < 8; ++j) {
      p[j]     = fmaf(m5[r], wtr[j], p[j]);
      p[8 + j] = fmaf(m2[r], wbr[j], p[8 + j]);
    }
  }
#pragma unroll
  for (int o = 32; o >= 1; o >>= 1) {
#pragma unroll
    for (int j = 0; j < 16; ++j) p[j] += __shfl_xor(p[j], o, 64);
  }
  if (lane == 0) {
#pragma unroll
    for (int j = 0; j < 8; ++j) {
      tvec[(size_t)n * 8 + j] = p[j] + bt[j];
      bvec[(size_t)n * 8 + j] = p[8 + j] + bb[j];
    }
  }
}

extern "C" void kernel_launch(void* const* d_in, const int* in_sizes, int n_in,
                              void* d_out, int out_size, void* d_ws, size_t ws_size,
                              hipStream_t stream)
{
  const int N_ = N_NODES;
  const int E_ = N_EDGES;

  const float* h = (const float*)d_in[0];
  const float* Wt = (const float*)d_in[28];
  const float* bt = (const float*)d_in[29];
  const float* Wb = (const float*)d_in[30];
  const float* bb = (const float*)d_in[31];
  const float* Wp = (const float*)d_in[32];
  const float* bp = (const float*)d_in[33];
  float* out = (float*)d_out;

  char* wsb = (char*)d_ws;
  size_t o = 0;
  auto alloc = [&](size_t bytes) -> void* {
    void* p = wsb + o;
    o = (o + bytes + 255) & ~(size_t)255;
    return p;
  };
  f16*  hf    = (f16*)alloc((size_t)N_ * 256 * 2);
  f16*  feat  = (f16*)alloc((size_t)N_ * 256 * 2);
  f16*  gat   = (f16*)alloc((size_t)N_ * 256 * 2);
  f16*  WT    = (f16*)alloc((size_t)3 * 256 * 256 * 2);
  f16*  WpT   = (f16*)alloc((size_t)256 * 256 * 2);
  float* el     = (float*)alloc((size_t)N_ * 4 * 4);
  float* er     = (float*)alloc((size_t)N_ * 4 * 4);
  float* tvec   = (float*)alloc((size_t)N_ * 8 * 4);
  float* bvec   = (float*)alloc((size_t)N_ * 8 * 4);
  int*   off    = (int*)alloc((size_t)(N_ + 1) * 4);
  int*   cursor = (int*)alloc((size_t)N_ * 4);
  int*   eid    = (int*)alloc((size_t)E_ * 4);
  (void)ws_size; (void)in_sizes; (void)n_in; (void)out_size;

  const int row_blocks = (N_ + 63) / 64;    // 469
  const int edge_blocks = (E_ + 255) / 256; // 1875
  const int wave_blocks = (N_ + 3) / 4;     // 7500

  // one-time conversions
  convert_h_kernel<<<(N_ * 256 / 8 + 255) / 256, 256, 0, stream>>>(h, hf, N_ * 256 / 8);
  for (int et = 0; et < 3; ++et)
    transpose_w_kernel<<<256, 256, 0, stream>>>((const float*)d_in[1 + et * 9 + 5],
                                                WT + (size_t)et * 256 * 256);
  transpose_w_kernel<<<256, 256, 0, stream>>>(Wp, WpT);

  for (int et = 0; et < 3; ++et) {
    const int base = 1 + et * 9;
    const int* src = (const int*)d_in[base + 0];
    const int* dst = (const int*)d_in[base + 1];
    const float* ew = (const float*)d_in[base + 2];
    const int* nbr_idx = (const int*)d_in[base + 3];
    const float* nbr_w = (const float*)d_in[base + 4];
    const float* al = (const float*)d_in[base + 6];
    const float* ar = (const float*)d_in[base + 7];
    const float* b = (const float*)d_in[base + 8];

    hipMemsetAsync(cursor, 0, (size_t)N_ * sizeof(int), stream);

    gemm_mfma<0><<<dim3(row_blocks, 4), 256, 0, stream>>>(
        hf, WT + (size_t)et * 256 * 256, feat, nullptr, N_, al, ar, el, er,
        nullptr, nullptr, nullptr, nullptr, nullptr, 256, 0);

    count_kernel<<<edge_blocks, 256, 0, stream>>>(dst, cursor, E_);

    scan_kernel<<<1, 1024, 0, stream>>>(cursor, off, N_, E_);

    fill_kernel<<<edge_blocks, 256, 0, stream>>>(dst, cursor, eid, E_);

    aggregate_kernel<<<N_, 256, 0, stream>>>(
        off, eid, src, ew, el, er, (const __half*)feat, b, (__half*)gat);

    enhance_pool_kernel<<<wave_blocks, 256, 0, stream>>>(
        nbr_idx, nbr_w, (const __half*)gat, Wt, bt, Wb, bb, tvec, bvec, N_);

    gemm_mfma<1><<<dim3(row_blocks, 4), 256, 0, stream>>>(
        gat, WpT, nullptr, out, N_, nullptr, nullptr, nullptr, nullptr,
        tvec, bvec, Wp + 256 * 256, Wp + 264 * 256, bp, 768, et * 256);
  }
}

// Round 4
// 717.632 us; speedup vs baseline: 2.6569x; 1.0577x over previous
//
#include <hip/hip_runtime.h>
#include <hip/hip_fp16.h>

#define N_NODES 30000
#define N_EDGES 480000

typedef _Float16 f16;
typedef f16 f16x8 __attribute__((ext_vector_type(8)));
typedef float f32x4 __attribute__((ext_vector_type(4)));

// ================= one-time converts =================
__global__ void convert_h_kernel(const float* __restrict__ in, f16* __restrict__ out, int n8)
{
  int i = blockIdx.x * 256 + threadIdx.x;
  if (i >= n8) return;
  float4 a = *(const float4*)(in + (size_t)i * 8);
  float4 b = *(const float4*)(in + (size_t)i * 8 + 4);
  f16x8 v;
  v[0] = (f16)a.x; v[1] = (f16)a.y; v[2] = (f16)a.z; v[3] = (f16)a.w;
  v[4] = (f16)b.x; v[5] = (f16)b.y; v[6] = (f16)b.z; v[7] = (f16)b.w;
  *(f16x8*)(out + (size_t)i * 8) = v;
}

// out[m][n][k] = (f16) in_m[k][n], 4 matrices 256x256, blockIdx.y = m
__global__ void transpose_w_kernel(const float* __restrict__ s0, const float* __restrict__ s1,
                                   const float* __restrict__ s2, const float* __restrict__ s3,
                                   f16* __restrict__ out)
{
  int m = blockIdx.y;
  const float* in = (m == 0) ? s0 : (m == 1) ? s1 : (m == 2) ? s2 : s3;
  int t = blockIdx.x * 256 + threadIdx.x;   // 65536
  int n = t >> 8, k = t & 255;
  out[(size_t)m * 65536 + t] = (f16)in[k * 256 + n];
}

// ================= MFMA GEMM: 64x64 tile, f16 in, f32 acc =================
// MODE 0: feat(f16) = A@B; epilogue el/er (col-tile == head)
// MODE 1: out(f32) = A@B + t@Wp1 + bo@Wp2 + bp, strided store
template<int MODE>
__global__ __launch_bounds__(256)
void gemm_mfma(const f16* __restrict__ A, const f16* __restrict__ BT,
               f16* __restrict__ Ch, float* __restrict__ Cf, int M,
               const float* __restrict__ al, const float* __restrict__ ar,
               float* __restrict__ el, float* __restrict__ er,
               const float* __restrict__ tvec, const float* __restrict__ bvec,
               const float* __restrict__ Wp1, const float* __restrict__ Wp2,
               const float* __restrict__ bp, int ldc, int coff)
{
  __shared__ alignas(16) f16 As[64][40];
  __shared__ alignas(16) f16 Bs[64][40];
  __shared__ float W1s[8][64];
  __shared__ float W2s[8][64];
  __shared__ float t_lds[64][8];
  __shared__ float b_lds[64][8];

  const int tid = threadIdx.x;
  const int lane = tid & 63, wv = tid >> 6;
  const int l15 = lane & 15, lq = lane >> 4;
  const int bm = blockIdx.x * 64;
  const int ct = blockIdx.y;
  const int bn = ct * 64;

  if (MODE == 1) {
    if (tid < 128) {
      int r = tid >> 4, c4 = (tid & 15) * 4;
      *(float4*)&W1s[r][c4] = *(const float4*)&Wp1[r * 256 + bn + c4];
    } else {
      int t2 = tid - 128;
      int r = t2 >> 4, c4 = (t2 & 15) * 4;
      *(float4*)&W2s[r][c4] = *(const float4*)&Wp2[r * 256 + bn + c4];
    }
    {
      int r = tid >> 2, c = (tid & 3) * 2;
      int row = bm + r;
      float2 tv = make_float2(0.f, 0.f), bv2 = make_float2(0.f, 0.f);
      if (row < M) {
        tv  = *(const float2*)&tvec[(size_t)row * 8 + c];
        bv2 = *(const float2*)&bvec[(size_t)row * 8 + c];
      }
      t_lds[r][c] = tv.x;  t_lds[r][c + 1] = tv.y;
      b_lds[r][c] = bv2.x; b_lds[r][c + 1] = bv2.y;
    }
  }

  const int arow = tid >> 2, k8 = (tid & 3) * 8;
  const bool arow_ok = (bm + arow) < M;
  const f16* Aptr = A + (size_t)(bm + arow) * 256 + k8;
  const f16* Bptr = BT + (size_t)(bn + arow) * 256 + k8;

  f32x4 acc[4] = {};   // 4 N-frags of 16 cols each

  for (int k0 = 0; k0 < 256; k0 += 32) {
    uint4 av = make_uint4(0u, 0u, 0u, 0u);
    if (arow_ok) av = *(const uint4*)(Aptr + k0);
    uint4 bv = *(const uint4*)(Bptr + k0);
    __syncthreads();
    *(uint4*)&As[arow][k8] = av;
    *(uint4*)&Bs[arow][k8] = bv;
    __syncthreads();
    f16x8 af = *(const f16x8*)&As[wv * 16 + l15][lq * 8];
#pragma unroll
    for (int nf = 0; nf < 4; ++nf) {
      f16x8 bf = *(const f16x8*)&Bs[nf * 16 + l15][lq * 8];
      acc[nf] = __builtin_amdgcn_mfma_f32_16x16x32_f16(af, bf, acc[nf], 0, 0, 0);
    }
  }

  if (MODE == 0) {
    float alv[4], arv[4];
#pragma unroll
    for (int nf = 0; nf < 4; ++nf) {
      alv[nf] = al[bn + nf * 16 + l15];
      arv[nf] = ar[bn + nf * 16 + l15];
    }
#pragma unroll
    for (int i = 0; i < 4; ++i) {
      int row = bm + wv * 16 + lq * 4 + i;
      float pe = 0.f, pr = 0.f;
#pragma unroll
      for (int nf = 0; nf < 4; ++nf) {
        pe = fmaf(acc[nf][i], alv[nf], pe);
        pr = fmaf(acc[nf][i], arv[nf], pr);
      }
#pragma unroll
      for (int o = 8; o >= 1; o >>= 1) {
        pe += __shfl_xor(pe, o, 64);
        pr += __shfl_xor(pr, o, 64);
      }
      if (row < M) {
        if (l15 == 0) {
          el[row * 4 + ct] = pe;
          er[row * 4 + ct] = pr;
        }
#pragma unroll
        for (int nf = 0; nf < 4; ++nf)
          Ch[(size_t)row * 256 + bn + nf * 16 + l15] = (f16)acc[nf][i];
      }
    }
  } else {
    float bpv[4];
#pragma unroll
    for (int nf = 0; nf < 4; ++nf) bpv[nf] = bp[bn + nf * 16 + l15];
#pragma unroll
    for (int i = 0; i < 4; ++i) {
      int rl = wv * 16 + lq * 4 + i;
      int row = bm + rl;
      if (row >= M) continue;
#pragma unroll
      for (int nf = 0; nf < 4; ++nf) {
        int c = nf * 16 + l15;
        float v = acc[nf][i] + bpv[nf];
#pragma unroll
        for (int k = 0; k < 8; ++k) {
          v = fmaf(t_lds[rl][k], W1s[k][c], v);
          v = fmaf(b_lds[rl][k], W2s[k][c], v);
        }
        Cf[(size_t)row * ldc + coff + bn + c] = v;
      }
    }
  }
}

// ============== batched count (blockIdx.y = etype) ==============
__global__ void count_kernel(const int* __restrict__ d0, const int* __restrict__ d1,
                             const int* __restrict__ d2, int* cursor, int ne, int n)
{
  int et = blockIdx.y;
  const int* dst = (et == 0) ? d0 : (et == 1) ? d1 : d2;
  int e = blockIdx.x * 256 + threadIdx.x;
  if (e < ne) atomicAdd(&cursor[et * n + dst[e]], 1);
}

// ============== batched scan (blockIdx.x = etype) ==============
__global__ __launch_bounds__(1024)
void scan_kernel(int* __restrict__ cc_all, int* __restrict__ off_all, int n, int total)
{
  int et = blockIdx.x;
  int* cc = cc_all + (size_t)et * n;
  int* off = off_all + (size_t)et * (n + 1);
  __shared__ int wsum[16];
  __shared__ int woff[16];
  __shared__ int s_carry, s_chunk;
  int tid = threadIdx.x;
  int lane = tid & 63, wid = tid >> 6;
  if (tid == 0) s_carry = 0;
  __syncthreads();
  for (int base = 0; base < n; base += 1024) {
    int i = base + tid;
    int v = (i < n) ? cc[i] : 0;
    int x = v;
#pragma unroll
    for (int s = 1; s < 64; s <<= 1) {
      int y = __shfl_up(x, s, 64);
      if (lane >= s) x += y;
    }
    if (lane == 63) wsum[wid] = x;
    __syncthreads();
    if (wid == 0 && lane < 16) {
      int ws_ = wsum[lane];
      int xx = ws_;
#pragma unroll
      for (int s = 1; s < 16; s <<= 1) {
        int y = __shfl_up(xx, s, 64);
        if (lane >= s) xx += y;
      }
      woff[lane] = xx - ws_;
      if (lane == 15) s_chunk = xx;
    }
    __syncthreads();
    int excl = s_carry + woff[wid] + (x - v);
    if (i < n) { off[i] = excl; cc[i] = excl; }
    __syncthreads();
    if (tid == 0) s_carry += s_chunk;
    __syncthreads();
  }
  if (tid == 0) off[n] = total;
}

// ============== batched CSR fill ==============
__global__ void fill_kernel(const int* __restrict__ d0, const int* __restrict__ d1,
                            const int* __restrict__ d2, int* cursor,
                            int* __restrict__ eid, int ne, int n)
{
  int et = blockIdx.y;
  const int* dst = (et == 0) ? d0 : (et == 1) ? d1 : d2;
  int e = blockIdx.x * 256 + threadIdx.x;
  if (e >= ne) return;
  int p = atomicAdd(&cursor[et * n + dst[e]], 1);
  eid[(size_t)et * ne + p] = e;
}

// ============== per-dst aggregation (softmax in-block, atomic-free) ==============
__global__ __launch_bounds__(256)
void aggregate_kernel(const int* __restrict__ off, const int* __restrict__ eid,
                      const int* __restrict__ src, const float* __restrict__ ew,
                      const float* __restrict__ el, const float* __restrict__ er,
                      const __half* __restrict__ feat, const float* __restrict__ bias,
                      __half* __restrict__ gat)
{
  int n = blockIdx.x;
  int tid = threadIdx.x;
  int lane = tid & 63, wv = tid >> 6;
  int hd = lane >> 4;                    // head of this lane's 4-column slice
  __shared__ int s_src[256];
  __shared__ float s_coef[256][4];       // ex * ew
  __shared__ float s_ex[256][4];         // ex (for denom)
  __shared__ float red[4][256];
  __shared__ float sdn[4];
  int e0 = off[n], e1 = off[n + 1];
  float4 er4 = *(const float4*)&er[(size_t)n * 4];
  if (tid < 4) sdn[tid] = 0.f;
  float ac0 = 0.f, ac1 = 0.f, ac2 = 0.f, ac3 = 0.f;

  for (int base = e0; base < e1; base += 256) {
    int cnt = min(256, e1 - base);
    __syncthreads();
    if (tid < cnt) {
      int e = eid[base + tid];
      int s = src[e];
      s_src[tid] = s;
      float w = ew[e];
      float4 l4 = *(const float4*)&el[(size_t)s * 4];
      float v0 = l4.x + er4.x; v0 = v0 > 0.f ? v0 : 0.2f * v0;
      float v1 = l4.y + er4.y; v1 = v1 > 0.f ? v1 : 0.2f * v1;
      float v2 = l4.z + er4.z; v2 = v2 > 0.f ? v2 : 0.2f * v2;
      float v3 = l4.w + er4.w; v3 = v3 > 0.f ? v3 : 0.2f * v3;
      float x0 = __expf(v0), x1 = __expf(v1), x2 = __expf(v2), x3 = __expf(v3);
      s_ex[tid][0] = x0; s_ex[tid][1] = x1; s_ex[tid][2] = x2; s_ex[tid][3] = x3;
      s_coef[tid][0] = x0 * w; s_coef[tid][1] = x1 * w;
      s_coef[tid][2] = x2 * w; s_coef[tid][3] = x3 * w;
    }
    __syncthreads();
    if (wv == 0) {
      float p = 0.f;
      for (int k = lane >> 2; k < cnt; k += 16) p += s_ex[k][lane & 3];
      p += __shfl_xor(p, 4, 64);
      p += __shfl_xor(p, 8, 64);
      p += __shfl_xor(p, 16, 64);
      p += __shfl_xor(p, 32, 64);
      if (lane < 4) sdn[lane] += p;
    }
    int k = wv;
    for (; k + 12 < cnt; k += 16) {
      int sA = s_src[k], sB = s_src[k + 4], sC = s_src[k + 8], sD = s_src[k + 12];
      float cA = s_coef[k][hd];
      float cB = s_coef[k + 4][hd];
      float cC = s_coef[k + 8][hd];
      float cD = s_coef[k + 12][hd];
      uint2 uA = *(const uint2*)(feat + (size_t)sA * 256 + lane * 4);
      uint2 uB = *(const uint2*)(feat + (size_t)sB * 256 + lane * 4);
      uint2 uC = *(const uint2*)(feat + (size_t)sC * 256 + lane * 4);
      uint2 uD = *(const uint2*)(feat + (size_t)sD * 256 + lane * 4);
      float2 A01 = __half22float2(*(__half2*)&uA.x), A23 = __half22float2(*(__half2*)&uA.y);
      float2 B01 = __half22float2(*(__half2*)&uB.x), B23 = __half22float2(*(__half2*)&uB.y);
      float2 C01 = __half22float2(*(__half2*)&uC.x), C23 = __half22float2(*(__half2*)&uC.y);
      float2 D01 = __half22float2(*(__half2*)&uD.x), D23 = __half22float2(*(__half2*)&uD.y);
      ac0 = fmaf(cA, A01.x, ac0); ac1 = fmaf(cA, A01.y, ac1);
      ac2 = fmaf(cA, A23.x, ac2); ac3 = fmaf(cA, A23.y, ac3);
      ac0 = fmaf(cB, B01.x, ac0); ac1 = fmaf(cB, B01.y, ac1);
      ac2 = fmaf(cB, B23.x, ac2); ac3 = fmaf(cB, B23.y, ac3);
      ac0 = fmaf(cC, C01.x, ac0); ac1 = fmaf(cC, C01.y, ac1);
      ac2 = fmaf(cC, C23.x, ac2); ac3 = fmaf(cC, C23.y, ac3);
      ac0 = fmaf(cD, D01.x, ac0); ac1 = fmaf(cD, D01.y, ac1);
      ac2 = fmaf(cD, D23.x, ac2); ac3 = fmaf(cD, D23.y, ac3);
    }
    for (; k < cnt; k += 4) {
      int s0 = s_src[k];
      float c0 = s_coef[k][hd];
      uint2 u = *(const uint2*)(feat + (size_t)s0 * 256 + lane * 4);
      float2 f01 = __half22float2(*(__half2*)&u.x), f23 = __half22float2(*(__half2*)&u.y);
      ac0 = fmaf(c0, f01.x, ac0); ac1 = fmaf(c0, f01.y, ac1);
      ac2 = fmaf(c0, f23.x, ac2); ac3 = fmaf(c0, f23.y, ac3);
    }
  }
  red[wv][lane * 4 + 0] = ac0;
  red[wv][lane * 4 + 1] = ac1;
  red[wv][lane * 4 + 2] = ac2;
  red[wv][lane * 4 + 3] = ac3;
  __syncthreads();
  float dn = sdn[tid >> 6];
  float invd = (dn != 0.f) ? 1.f / dn : 0.f;
  float v = (red[0][tid] + red[1][tid] + red[2][tid] + red[3][tid]) * invd + bias[tid];
  gat[(size_t)n * 256 + tid] = __float2half_rn(v);
}

// ============== gt = gat@Wt, gb = gat@Wb  ([N,8] each, f32) ==============
__global__ __launch_bounds__(256)
void project_tb_kernel(const __half* __restrict__ gat,
                       const float* __restrict__ Wt, const float* __restrict__ Wb,
                       float* __restrict__ gt, float* __restrict__ gb, int n_nodes)
{
  int node = (blockIdx.x * 256 + threadIdx.x) >> 6;
  int lane = threadIdx.x & 63;
  if (node >= n_nodes) return;
  uint2 u = *(const uint2*)(gat + (size_t)node * 256 + lane * 4);
  float2 f01 = __half22float2(*(__half2*)&u.x);
  float2 f23 = __half22float2(*(__half2*)&u.y);
  float f[4] = {f01.x, f01.y, f23.x, f23.y};
  float p[16];
#pragma unroll
  for (int j = 0; j < 16; ++j) p[j] = 0.f;
#pragma unroll
  for (int r = 0; r < 4; ++r) {
    int c = lane * 4 + r;
    const float* wtr = &Wt[(size_t)c * 8];
    const float* wbr = &Wb[(size_t)c * 8];
#pragma unroll
    for (int j = 0; j < 8; ++j) {
      p[j]     = fmaf(f[r], wtr[j], p[j]);
      p[8 + j] = fmaf(f[r], wbr[j], p[8 + j]);
    }
  }
#pragma unroll
  for (int o = 32; o >= 1; o >>= 1) {
#pragma unroll
    for (int j = 0; j < 16; ++j) p[j] += __shfl_xor(p[j], o, 64);
  }
  if (lane == 0) {
    *(float4*)&gt[(size_t)node * 8]     = make_float4(p[0], p[1], p[2], p[3]);
    *(float4*)&gt[(size_t)node * 8 + 4] = make_float4(p[4], p[5], p[6], p[7]);
    *(float4*)&gb[(size_t)node * 8]     = make_float4(p[8], p[9], p[10], p[11]);
    *(float4*)&gb[(size_t)node * 8 + 4] = make_float4(p[12], p[13], p[14], p[15]);
  }
}

// ============== enhance: wave-per-node; rank + tiny gt/gb gathers ==============
__global__ __launch_bounds__(256)
void enhance_pool_kernel(const int* __restrict__ nbr_idx, const float* __restrict__ nbr_w,
                         const float* __restrict__ gt, const float* __restrict__ gb,
                         const float* __restrict__ bt, const float* __restrict__ bb,
                         float* __restrict__ tvec, float* __restrict__ bvec, int n_nodes)
{
  int n = (blockIdx.x * 256 + threadIdx.x) >> 6;
  int lane = threadIdx.x & 63;
  if (n >= n_nodes) return;
  const int l16 = lane & 15;

  float w = nbr_w[(size_t)n * 16 + l16];
  int idx = nbr_idx[(size_t)n * 16 + l16];

  int rhi = 0, rlo = 0;
#pragma unroll
  for (int i = 0; i < 16; ++i) {
    float wi = __shfl(w, i, 64);
    rhi += (wi > w) || (wi == w && i < l16);
    rlo += (wi < w) || (wi == w && i < l16);
  }

  int rows[7];
#pragma unroll
  for (int q = 0; q < 5; ++q) {
    unsigned long long m = __ballot(lane < 16 && rhi == q);
    rows[q] = __shfl(idx, __ffsll(m) - 1, 64);
  }
#pragma unroll
  for (int q = 0; q < 2; ++q) {
    unsigned long long m = __ballot(lane < 16 && rlo == q);
    rows[5 + q] = __shfl(idx, __ffsll(m) - 1, 64);
  }

  int j = lane & 7;
  if (lane < 8) {
    float s = 0.f;
#pragma unroll
    for (int q = 0; q < 5; ++q) s += gt[(size_t)rows[q] * 8 + j];
    tvec[(size_t)n * 8 + j] = s * 0.2f + bt[j];
  } else if (lane < 16) {
    float s = gb[(size_t)rows[5] * 8 + j] + gb[(size_t)rows[6] * 8 + j];
    bvec[(size_t)n * 8 + j] = s * 0.5f + bb[j];
  }
}

extern "C" void kernel_launch(void* const* d_in, const int* in_sizes, int n_in,
                              void* d_out, int out_size, void* d_ws, size_t ws_size,
                              hipStream_t stream)
{
  const int N_ = N_NODES;
  const int E_ = N_EDGES;

  const float* h = (const float*)d_in[0];
  const float* Wt = (const float*)d_in[28];
  const float* bt = (const float*)d_in[29];
  const float* Wb = (const float*)d_in[30];
  const float* bb = (const float*)d_in[31];
  const float* Wp = (const float*)d_in[32];
  const float* bp = (const float*)d_in[33];
  float* out = (float*)d_out;

  char* wsb = (char*)d_ws;
  size_t o = 0;
  auto alloc = [&](size_t bytes) -> void* {
    void* p = wsb + o;
    o = (o + bytes + 255) & ~(size_t)255;
    return p;
  };
  f16*  hf    = (f16*)alloc((size_t)N_ * 256 * 2);
  f16*  feat  = (f16*)alloc((size_t)N_ * 256 * 2);
  f16*  gat   = (f16*)alloc((size_t)N_ * 256 * 2);
  f16*  WT    = (f16*)alloc((size_t)4 * 256 * 256 * 2);   // 3x W + WpT
  float* el     = (float*)alloc((size_t)N_ * 4 * 4);
  float* er     = (float*)alloc((size_t)N_ * 4 * 4);
  float* gt     = (float*)alloc((size_t)N_ * 8 * 4);
  float* gb     = (float*)alloc((size_t)N_ * 8 * 4);
  float* tvec   = (float*)alloc((size_t)N_ * 8 * 4);
  float* bvec   = (float*)alloc((size_t)N_ * 8 * 4);
  int*   off    = (int*)alloc((size_t)3 * (N_ + 1) * 4);
  int*   cursor = (int*)alloc((size_t)3 * N_ * 4);
  int*   eid    = (int*)alloc((size_t)3 * E_ * 4);
  (void)ws_size; (void)in_sizes; (void)n_in; (void)out_size;

  const int row_blocks = (N_ + 63) / 64;    // 469
  const int edge_blocks = (E_ + 255) / 256; // 1875
  const int wave_blocks = (N_ + 3) / 4;     // 7500

  const int* d_dst0 = (const int*)d_in[1 + 0 * 9 + 1];
  const int* d_dst1 = (const int*)d_in[1 + 1 * 9 + 1];
  const int* d_dst2 = (const int*)d_in[1 + 2 * 9 + 1];

  // one-time conversions + batched CSR build (independent of GEMMs)
  convert_h_kernel<<<(N_ * 256 / 8 + 255) / 256, 256, 0, stream>>>(h, hf, N_ * 256 / 8);
  transpose_w_kernel<<<dim3(256, 4), 256, 0, stream>>>(
      (const float*)d_in[1 + 0 * 9 + 5], (const float*)d_in[1 + 1 * 9 + 5],
      (const float*)d_in[1 + 2 * 9 + 5], Wp, WT);
  f16* WpT = WT + (size_t)3 * 65536;

  hipMemsetAsync(cursor, 0, (size_t)3 * N_ * sizeof(int), stream);
  count_kernel<<<dim3(edge_blocks, 3), 256, 0, stream>>>(d_dst0, d_dst1, d_dst2, cursor, E_, N_);
  scan_kernel<<<3, 1024, 0, stream>>>(cursor, off, N_, E_);
  fill_kernel<<<dim3(edge_blocks, 3), 256, 0, stream>>>(d_dst0, d_dst1, d_dst2, cursor, eid, E_, N_);

  for (int et = 0; et < 3; ++et) {
    const int base = 1 + et * 9;
    const int* src = (const int*)d_in[base + 0];
    const float* ew = (const float*)d_in[base + 2];
    const int* nbr_idx = (const int*)d_in[base + 3];
    const float* nbr_w = (const float*)d_in[base + 4];
    const float* al = (const float*)d_in[base + 6];
    const float* ar = (const float*)d_in[base + 7];
    const float* b = (const float*)d_in[base + 8];

    gemm_mfma<0><<<dim3(row_blocks, 4), 256, 0, stream>>>(
        hf, WT + (size_t)et * 65536, feat, nullptr, N_, al, ar, el, er,
        nullptr, nullptr, nullptr, nullptr, nullptr, 256, 0);

    aggregate_kernel<<<N_, 256, 0, stream>>>(
        off + (size_t)et * (N_ + 1), eid + (size_t)et * E_, src, ew, el, er,
        (const __half*)feat, b, (__half*)gat);

    project_tb_kernel<<<wave_blocks, 256, 0, stream>>>(
        (const __half*)gat, Wt, Wb, gt, gb, N_);

    enhance_pool_kernel<<<wave_blocks, 256, 0, stream>>>(
        nbr_idx, nbr_w, gt, gb, bt, bb, tvec, bvec, N_);

    gemm_mfma<1><<<dim3(row_blocks, 4), 256, 0, stream>>>(
        gat, WpT, nullptr, out, N_, nullptr, nullptr, nullptr, nullptr,
        tvec, bvec, Wp + 256 * 256, Wp + 264 * 256, bp, 768, et * 256);
  }
}

// Round 5
// 643.187 us; speedup vs baseline: 2.9645x; 1.1157x over previous
//
#include <hip/hip_runtime.h>
#include <hip/hip_fp16.h>

#define N_NODES 30000
#define N_EDGES 480000
#define NB 16           // blocks per etype for counting sort
#define CHUNK 30000     // N_EDGES / NB

typedef _Float16 f16;
typedef f16 f16x8 __attribute__((ext_vector_type(8)));
typedef float f32x4 __attribute__((ext_vector_type(4)));

// ================= one-time converts =================
__global__ void convert_h_kernel(const float* __restrict__ in, f16* __restrict__ out, int n8)
{
  int i = blockIdx.x * 256 + threadIdx.x;
  if (i >= n8) return;
  float4 a = *(const float4*)(in + (size_t)i * 8);
  float4 b = *(const float4*)(in + (size_t)i * 8 + 4);
  f16x8 v;
  v[0] = (f16)a.x; v[1] = (f16)a.y; v[2] = (f16)a.z; v[3] = (f16)a.w;
  v[4] = (f16)b.x; v[5] = (f16)b.y; v[6] = (f16)b.z; v[7] = (f16)b.w;
  *(f16x8*)(out + (size_t)i * 8) = v;
}

// out[m][n][k] = (f16) in_m[k][n], 4 matrices 256x256, blockIdx.y = m
__global__ void transpose_w_kernel(const float* __restrict__ s0, const float* __restrict__ s1,
                                   const float* __restrict__ s2, const float* __restrict__ s3,
                                   f16* __restrict__ out)
{
  int m = blockIdx.y;
  const float* in = (m == 0) ? s0 : (m == 1) ? s1 : (m == 2) ? s2 : s3;
  int t = blockIdx.x * 256 + threadIdx.x;   // 65536
  int n = t >> 8, k = t & 255;
  out[(size_t)m * 65536 + t] = (f16)in[k * 256 + n];
}

// ================= MFMA GEMM: 64x64 tile, f16 in, f32 acc =================
template<int MODE>
__global__ __launch_bounds__(256)
void gemm_mfma(const f16* __restrict__ A, const f16* __restrict__ BT,
               f16* __restrict__ Ch, float* __restrict__ Cf, int M,
               const float* __restrict__ al, const float* __restrict__ ar,
               float* __restrict__ el, float* __restrict__ er,
               const float* __restrict__ tvec, const float* __restrict__ bvec,
               const float* __restrict__ Wp1, const float* __restrict__ Wp2,
               const float* __restrict__ bp, int ldc, int coff)
{
  __shared__ alignas(16) f16 As[64][40];
  __shared__ alignas(16) f16 Bs[64][40];
  __shared__ float W1s[8][64];
  __shared__ float W2s[8][64];
  __shared__ float t_lds[64][8];
  __shared__ float b_lds[64][8];

  const int tid = threadIdx.x;
  const int lane = tid & 63, wv = tid >> 6;
  const int l15 = lane & 15, lq = lane >> 4;
  const int bm = blockIdx.x * 64;
  const int ct = blockIdx.y;
  const int bn = ct * 64;

  if (MODE == 1) {
    if (tid < 128) {
      int r = tid >> 4, c4 = (tid & 15) * 4;
      *(float4*)&W1s[r][c4] = *(const float4*)&Wp1[r * 256 + bn + c4];
    } else {
      int t2 = tid - 128;
      int r = t2 >> 4, c4 = (t2 & 15) * 4;
      *(float4*)&W2s[r][c4] = *(const float4*)&Wp2[r * 256 + bn + c4];
    }
    {
      int r = tid >> 2, c = (tid & 3) * 2;
      int row = bm + r;
      float2 tv = make_float2(0.f, 0.f), bv2 = make_float2(0.f, 0.f);
      if (row < M) {
        tv  = *(const float2*)&tvec[(size_t)row * 8 + c];
        bv2 = *(const float2*)&bvec[(size_t)row * 8 + c];
      }
      t_lds[r][c] = tv.x;  t_lds[r][c + 1] = tv.y;
      b_lds[r][c] = bv2.x; b_lds[r][c + 1] = bv2.y;
    }
  }

  const int arow = tid >> 2, k8 = (tid & 3) * 8;
  const bool arow_ok = (bm + arow) < M;
  const f16* Aptr = A + (size_t)(bm + arow) * 256 + k8;
  const f16* Bptr = BT + (size_t)(bn + arow) * 256 + k8;

  f32x4 acc[4] = {};   // 4 N-frags of 16 cols each

  for (int k0 = 0; k0 < 256; k0 += 32) {
    uint4 av = make_uint4(0u, 0u, 0u, 0u);
    if (arow_ok) av = *(const uint4*)(Aptr + k0);
    uint4 bv = *(const uint4*)(Bptr + k0);
    __syncthreads();
    *(uint4*)&As[arow][k8] = av;
    *(uint4*)&Bs[arow][k8] = bv;
    __syncthreads();
    f16x8 af = *(const f16x8*)&As[wv * 16 + l15][lq * 8];
#pragma unroll
    for (int nf = 0; nf < 4; ++nf) {
      f16x8 bf = *(const f16x8*)&Bs[nf * 16 + l15][lq * 8];
      acc[nf] = __builtin_amdgcn_mfma_f32_16x16x32_f16(af, bf, acc[nf], 0, 0, 0);
    }
  }

  if (MODE == 0) {
    float alv[4], arv[4];
#pragma unroll
    for (int nf = 0; nf < 4; ++nf) {
      alv[nf] = al[bn + nf * 16 + l15];
      arv[nf] = ar[bn + nf * 16 + l15];
    }
#pragma unroll
    for (int i = 0; i < 4; ++i) {
      int row = bm + wv * 16 + lq * 4 + i;
      float pe = 0.f, pr = 0.f;
#pragma unroll
      for (int nf = 0; nf < 4; ++nf) {
        pe = fmaf(acc[nf][i], alv[nf], pe);
        pr = fmaf(acc[nf][i], arv[nf], pr);
      }
#pragma unroll
      for (int o = 8; o >= 1; o >>= 1) {
        pe += __shfl_xor(pe, o, 64);
        pr += __shfl_xor(pr, o, 64);
      }
      if (row < M) {
        if (l15 == 0) {
          el[row * 4 + ct] = pe;
          er[row * 4 + ct] = pr;
        }
#pragma unroll
        for (int nf = 0; nf < 4; ++nf)
          Ch[(size_t)row * 256 + bn + nf * 16 + l15] = (f16)acc[nf][i];
      }
    }
  } else {
    float bpv[4];
#pragma unroll
    for (int nf = 0; nf < 4; ++nf) bpv[nf] = bp[bn + nf * 16 + l15];
#pragma unroll
    for (int i = 0; i < 4; ++i) {
      int rl = wv * 16 + lq * 4 + i;
      int row = bm + rl;
      if (row >= M) continue;
#pragma unroll
      for (int nf = 0; nf < 4; ++nf) {
        int c = nf * 16 + l15;
        float v = acc[nf][i] + bpv[nf];
#pragma unroll
        for (int k = 0; k < 8; ++k) {
          v = fmaf(t_lds[rl][k], W1s[k][c], v);
          v = fmaf(b_lds[rl][k], W2s[k][c], v);
        }
        Cf[(size_t)row * ldc + coff + bn + c] = v;
      }
    }
  }
}

// ============== CSR build pass 1: LDS histogram + per-edge local rank ==============
// grid (NB, 3), 256 threads. hist packed 2 x u16 per u32 (count <= CHUNK < 65536).
__global__ __launch_bounds__(256)
void hist_kernel(const int* __restrict__ d0, const int* __restrict__ d1,
                 const int* __restrict__ d2, int* __restrict__ ghist,
                 unsigned short* __restrict__ rank16)
{
  __shared__ unsigned int h32[N_NODES / 2];
  int et = blockIdx.y, b = blockIdx.x, tid = threadIdx.x;
  const int* dst = (et == 0) ? d0 : (et == 1) ? d1 : d2;
  for (int i = tid; i < N_NODES / 2; i += 256) h32[i] = 0u;
  __syncthreads();
  int e0 = b * CHUNK;
  for (int i = tid; i < CHUNK; i += 256) {
    int e = e0 + i;
    int d = dst[e];
    unsigned int sh = (d & 1) * 16;
    unsigned int old = atomicAdd(&h32[d >> 1], 1u << sh);
    rank16[(size_t)et * N_EDGES + e] = (unsigned short)((old >> sh) & 0xFFFFu);
  }
  __syncthreads();
  int* gh = ghist + ((size_t)(et * NB + b)) * N_NODES;
  for (int d = tid; d < N_NODES; d += 256)
    gh[d] = (int)((h32[d >> 1] >> ((d & 1) * 16)) & 0xFFFFu);
}

// ============== pass 2: per-dst exclusive prefix over NB blocks + totals ==============
// grid (118, 3), 256 threads
__global__ __launch_bounds__(256)
void blockpfx_kernel(int* __restrict__ ghist, int* __restrict__ counts)
{
  int d = blockIdx.x * 256 + threadIdx.x;
  int et = blockIdx.y;
  if (d >= N_NODES) return;
  int running = 0;
#pragma unroll
  for (int b = 0; b < NB; ++b) {
    size_t idx = ((size_t)(et * NB + b)) * N_NODES + d;
    int v = ghist[idx];
    ghist[idx] = running;
    running += v;
  }
  counts[et * N_NODES + d] = running;
}

// ============== batched scan (blockIdx.x = etype) ==============
__global__ __launch_bounds__(1024)
void scan_kernel(int* __restrict__ cc_all, int* __restrict__ off_all, int n, int total)
{
  int et = blockIdx.x;
  int* cc = cc_all + (size_t)et * n;
  int* off = off_all + (size_t)et * (n + 1);
  __shared__ int wsum[16];
  __shared__ int woff[16];
  __shared__ int s_carry, s_chunk;
  int tid = threadIdx.x;
  int lane = tid & 63, wid = tid >> 6;
  if (tid == 0) s_carry = 0;
  __syncthreads();
  for (int base = 0; base < n; base += 1024) {
    int i = base + tid;
    int v = (i < n) ? cc[i] : 0;
    int x = v;
#pragma unroll
    for (int s = 1; s < 64; s <<= 1) {
      int y = __shfl_up(x, s, 64);
      if (lane >= s) x += y;
    }
    if (lane == 63) wsum[wid] = x;
    __syncthreads();
    if (wid == 0 && lane < 16) {
      int ws_ = wsum[lane];
      int xx = ws_;
#pragma unroll
      for (int s = 1; s < 16; s <<= 1) {
        int y = __shfl_up(xx, s, 64);
        if (lane >= s) xx += y;
      }
      woff[lane] = xx - ws_;
      if (lane == 15) s_chunk = xx;
    }
    __syncthreads();
    int excl = s_carry + woff[wid] + (x - v);
    if (i < n) { off[i] = excl; cc[i] = excl; }
    __syncthreads();
    if (tid == 0) s_carry += s_chunk;
    __syncthreads();
  }
  if (tid == 0) off[n] = total;
}

// ============== pass 4: place payload (no atomics, full occupancy) ==============
// grid (1875, 3), 256 threads
__global__ __launch_bounds__(256)
void place_kernel(const int* __restrict__ d0, const int* __restrict__ d1,
                  const int* __restrict__ d2,
                  const int* __restrict__ s0, const int* __restrict__ s1,
                  const int* __restrict__ s2,
                  const float* __restrict__ w0, const float* __restrict__ w1,
                  const float* __restrict__ w2,
                  const int* __restrict__ off, const int* __restrict__ ghist,
                  const unsigned short* __restrict__ rank16,
                  int* __restrict__ csr_src, float* __restrict__ csr_ew)
{
  int e = blockIdx.x * 256 + threadIdx.x;
  if (e >= N_EDGES) return;
  int et = blockIdx.y;
  const int* dst = (et == 0) ? d0 : (et == 1) ? d1 : d2;
  const int* src = (et == 0) ? s0 : (et == 1) ? s1 : s2;
  const float* ew = (et == 0) ? w0 : (et == 1) ? w1 : w2;
  int d = dst[e];
  int b = e / CHUNK;
  int pos = off[et * (N_NODES + 1) + d]
          + ghist[((size_t)(et * NB + b)) * N_NODES + d]
          + (int)rank16[(size_t)et * N_EDGES + e];
  csr_src[(size_t)et * N_EDGES + pos] = src[e];
  csr_ew[(size_t)et * N_EDGES + pos] = ew[e];
}

// ============== per-dst aggregation (softmax in-block, atomic-free) ==============
__global__ __launch_bounds__(256)
void aggregate_kernel(const int* __restrict__ off, const int* __restrict__ csr_src,
                      const float* __restrict__ csr_ew,
                      const float* __restrict__ el, const float* __restrict__ er,
                      const __half* __restrict__ feat, const float* __restrict__ bias,
                      __half* __restrict__ gat)
{
  int n = blockIdx.x;
  int tid = threadIdx.x;
  int lane = tid & 63, wv = tid >> 6;
  int hd = lane >> 4;                    // head of this lane's 4-column slice
  __shared__ int s_src[256];
  __shared__ float s_coef[256][4];       // ex * ew
  __shared__ float s_ex[256][4];         // ex (for denom)
  __shared__ float red[4][256];
  __shared__ float sdn[4];
  int e0 = off[n], e1 = off[n + 1];
  float4 er4 = *(const float4*)&er[(size_t)n * 4];
  if (tid < 4) sdn[tid] = 0.f;
  float ac0 = 0.f, ac1 = 0.f, ac2 = 0.f, ac3 = 0.f;

  for (int base = e0; base < e1; base += 256) {
    int cnt = min(256, e1 - base);
    __syncthreads();
    if (tid < cnt) {
      int s = csr_src[base + tid];
      s_src[tid] = s;
      float w = csr_ew[base + tid];
      float4 l4 = *(const float4*)&el[(size_t)s * 4];
      float v0 = l4.x + er4.x; v0 = v0 > 0.f ? v0 : 0.2f * v0;
      float v1 = l4.y + er4.y; v1 = v1 > 0.f ? v1 : 0.2f * v1;
      float v2 = l4.z + er4.z; v2 = v2 > 0.f ? v2 : 0.2f * v2;
      float v3 = l4.w + er4.w; v3 = v3 > 0.f ? v3 : 0.2f * v3;
      float x0 = __expf(v0), x1 = __expf(v1), x2 = __expf(v2), x3 = __expf(v3);
      s_ex[tid][0] = x0; s_ex[tid][1] = x1; s_ex[tid][2] = x2; s_ex[tid][3] = x3;
      s_coef[tid][0] = x0 * w; s_coef[tid][1] = x1 * w;
      s_coef[tid][2] = x2 * w; s_coef[tid][3] = x3 * w;
    }
    __syncthreads();
    if (wv == 0) {
      float p = 0.f;
      for (int k = lane >> 2; k < cnt; k += 16) p += s_ex[k][lane & 3];
      p += __shfl_xor(p, 4, 64);
      p += __shfl_xor(p, 8, 64);
      p += __shfl_xor(p, 16, 64);
      p += __shfl_xor(p, 32, 64);
      if (lane < 4) sdn[lane] += p;
    }
    int k = wv;
    for (; k + 12 < cnt; k += 16) {
      int sA = s_src[k], sB = s_src[k + 4], sC = s_src[k + 8], sD = s_src[k + 12];
      float cA = s_coef[k][hd];
      float cB = s_coef[k + 4][hd];
      float cC = s_coef[k + 8][hd];
      float cD = s_coef[k + 12][hd];
      uint2 uA = *(const uint2*)(feat + (size_t)sA * 256 + lane * 4);
      uint2 uB = *(const uint2*)(feat + (size_t)sB * 256 + lane * 4);
      uint2 uC = *(const uint2*)(feat + (size_t)sC * 256 + lane * 4);
      uint2 uD = *(const uint2*)(feat + (size_t)sD * 256 + lane * 4);
      float2 A01 = __half22float2(*(__half2*)&uA.x), A23 = __half22float2(*(__half2*)&uA.y);
      float2 B01 = __half22float2(*(__half2*)&uB.x), B23 = __half22float2(*(__half2*)&uB.y);
      float2 C01 = __half22float2(*(__half2*)&uC.x), C23 = __half22float2(*(__half2*)&uC.y);
      float2 D01 = __half22float2(*(__half2*)&uD.x), D23 = __half22float2(*(__half2*)&uD.y);
      ac0 = fmaf(cA, A01.x, ac0); ac1 = fmaf(cA, A01.y, ac1);
      ac2 = fmaf(cA, A23.x, ac2); ac3 = fmaf(cA, A23.y, ac3);
      ac0 = fmaf(cB, B01.x, ac0); ac1 = fmaf(cB, B01.y, ac1);
      ac2 = fmaf(cB, B23.x, ac2); ac3 = fmaf(cB, B23.y, ac3);
      ac0 = fmaf(cC, C01.x, ac0); ac1 = fmaf(cC, C01.y, ac1);
      ac2 = fmaf(cC, C23.x, ac2); ac3 = fmaf(cC, C23.y, ac3);
      ac0 = fmaf(cD, D01.x, ac0); ac1 = fmaf(cD, D01.y, ac1);
      ac2 = fmaf(cD, D23.x, ac2); ac3 = fmaf(cD, D23.y, ac3);
    }
    for (; k < cnt; k += 4) {
      int s0 = s_src[k];
      float c0 = s_coef[k][hd];
      uint2 u = *(const uint2*)(feat + (size_t)s0 * 256 + lane * 4);
      float2 f01 = __half22float2(*(__half2*)&u.x), f23 = __half22float2(*(__half2*)&u.y);
      ac0 = fmaf(c0, f01.x, ac0); ac1 = fmaf(c0, f01.y, ac1);
      ac2 = fmaf(c0, f23.x, ac2); ac3 = fmaf(c0, f23.y, ac3);
    }
  }
  red[wv][lane * 4 + 0] = ac0;
  red[wv][lane * 4 + 1] = ac1;
  red[wv][lane * 4 + 2] = ac2;
  red[wv][lane * 4 + 3] = ac3;
  __syncthreads();
  float dn = sdn[tid >> 6];
  float invd = (dn != 0.f) ? 1.f / dn : 0.f;
  float v = (red[0][tid] + red[1][tid] + red[2][tid] + red[3][tid]) * invd + bias[tid];
  gat[(size_t)n * 256 + tid] = __float2half_rn(v);
}

// ============== gt = gat@Wt, gb = gat@Wb  ([N,8] each, f32) ==============
__global__ __launch_bounds__(256)
void project_tb_kernel(const __half* __restrict__ gat,
                       const float* __restrict__ Wt, const float* __restrict__ Wb,
                       float* __restrict__ gt, float* __restrict__ gb, int n_nodes)
{
  int node = (blockIdx.x * 256 + threadIdx.x) >> 6;
  int lane = threadIdx.x & 63;
  if (node >= n_nodes) return;
  uint2 u = *(const uint2*)(gat + (size_t)node * 256 + lane * 4);
  float2 f01 = __half22float2(*(__half2*)&u.x);
  float2 f23 = __half22float2(*(__half2*)&u.y);
  float f[4] = {f01.x, f01.y, f23.x, f23.y};
  float p[16];
#pragma unroll
  for (int j = 0; j < 16; ++j) p[j] = 0.f;
#pragma unroll
  for (int r = 0; r < 4; ++r) {
    int c = lane * 4 + r;
    const float* wtr = &Wt[(size_t)c * 8];
    const float* wbr = &Wb[(size_t)c * 8];
#pragma unroll
    for (int j = 0; j < 8; ++j) {
      p[j]     = fmaf(f[r], wtr[j], p[j]);
      p[8 + j] = fmaf(f[r], wbr[j], p[8 + j]);
    }
  }
#pragma unroll
  for (int o = 32; o >= 1; o >>= 1) {
#pragma unroll
    for (int j = 0; j < 16; ++j) p[j] += __shfl_xor(p[j], o, 64);
  }
  if (lane == 0) {
    *(float4*)&gt[(size_t)node * 8]     = make_float4(p[0], p[1], p[2], p[3]);
    *(float4*)&gt[(size_t)node * 8 + 4] = make_float4(p[4], p[5], p[6], p[7]);
    *(float4*)&gb[(size_t)node * 8]     = make_float4(p[8], p[9], p[10], p[11]);
    *(float4*)&gb[(size_t)node * 8 + 4] = make_float4(p[12], p[13], p[14], p[15]);
  }
}

// ============== enhance: wave-per-node; rank + tiny gt/gb gathers ==============
__global__ __launch_bounds__(256)
void enhance_pool_kernel(const int* __restrict__ nbr_idx, const float* __restrict__ nbr_w,
                         const float* __restrict__ gt, const float* __restrict__ gb,
                         const float* __restrict__ bt, const float* __restrict__ bb,
                         float* __restrict__ tvec, float* __restrict__ bvec, int n_nodes)
{
  int n = (blockIdx.x * 256 + threadIdx.x) >> 6;
  int lane = threadIdx.x & 63;
  if (n >= n_nodes) return;
  const int l16 = lane & 15;

  float w = nbr_w[(size_t)n * 16 + l16];
  int idx = nbr_idx[(size_t)n * 16 + l16];

  int rhi = 0, rlo = 0;
#pragma unroll
  for (int i = 0; i < 16; ++i) {
    float wi = __shfl(w, i, 64);
    rhi += (wi > w) || (wi == w && i < l16);
    rlo += (wi < w) || (wi == w && i < l16);
  }

  int rows[7];
#pragma unroll
  for (int q = 0; q < 5; ++q) {
    unsigned long long m = __ballot(lane < 16 && rhi == q);
    rows[q] = __shfl(idx, __ffsll(m) - 1, 64);
  }
#pragma unroll
  for (int q = 0; q < 2; ++q) {
    unsigned long long m = __ballot(lane < 16 && rlo == q);
    rows[5 + q] = __shfl(idx, __ffsll(m) - 1, 64);
  }

  int j = lane & 7;
  if (lane < 8) {
    float s = 0.f;
#pragma unroll
    for (int q = 0; q < 5; ++q) s += gt[(size_t)rows[q] * 8 + j];
    tvec[(size_t)n * 8 + j] = s * 0.2f + bt[j];
  } else if (lane < 16) {
    float s = gb[(size_t)rows[5] * 8 + j] + gb[(size_t)rows[6] * 8 + j];
    bvec[(size_t)n * 8 + j] = s * 0.5f + bb[j];
  }
}

extern "C" void kernel_launch(void* const* d_in, const int* in_sizes, int n_in,
                              void* d_out, int out_size, void* d_ws, size_t ws_size,
                              hipStream_t stream)
{
  const int N_ = N_NODES;
  const int E_ = N_EDGES;

  const float* h = (const float*)d_in[0];
  const float* Wt = (const float*)d_in[28];
  const float* bt = (const float*)d_in[29];
  const float* Wb = (const float*)d_in[30];
  const float* bb = (const float*)d_in[31];
  const float* Wp = (const float*)d_in[32];
  const float* bp = (const float*)d_in[33];
  float* out = (float*)d_out;

  char* wsb = (char*)d_ws;
  size_t o = 0;
  auto alloc = [&](size_t bytes) -> void* {
    void* p = wsb + o;
    o = (o + bytes + 255) & ~(size_t)255;
    return p;
  };
  f16*  hf    = (f16*)alloc((size_t)N_ * 256 * 2);
  f16*  feat  = (f16*)alloc((size_t)N_ * 256 * 2);
  f16*  gat   = (f16*)alloc((size_t)N_ * 256 * 2);
  f16*  WT    = (f16*)alloc((size_t)4 * 256 * 256 * 2);   // 3x W + WpT
  float* el     = (float*)alloc((size_t)N_ * 4 * 4);
  float* er     = (float*)alloc((size_t)N_ * 4 * 4);
  float* gt     = (float*)alloc((size_t)N_ * 8 * 4);
  float* gb     = (float*)alloc((size_t)N_ * 8 * 4);
  float* tvec   = (float*)alloc((size_t)N_ * 8 * 4);
  float* bvec   = (float*)alloc((size_t)N_ * 8 * 4);
  int*   off    = (int*)alloc((size_t)3 * (N_ + 1) * 4);
  int*   counts = (int*)alloc((size_t)3 * N_ * 4);
  int*   ghist  = (int*)alloc((size_t)3 * NB * N_ * 4);          // 5.76 MB
  unsigned short* rank16 = (unsigned short*)alloc((size_t)3 * E_ * 2);
  int*   csr_src = (int*)alloc((size_t)3 * E_ * 4);
  float* csr_ew  = (float*)alloc((size_t)3 * E_ * 4);
  (void)ws_size; (void)in_sizes; (void)n_in; (void)out_size;

  const int row_blocks = (N_ + 63) / 64;    // 469
  const int edge_blocks = (E_ + 255) / 256; // 1875
  const int wave_blocks = (N_ + 3) / 4;     // 7500

  const int* d_dst0 = (const int*)d_in[1 + 0 * 9 + 1];
  const int* d_dst1 = (const int*)d_in[1 + 1 * 9 + 1];
  const int* d_dst2 = (const int*)d_in[1 + 2 * 9 + 1];
  const int* d_src0 = (const int*)d_in[1 + 0 * 9 + 0];
  const int* d_src1 = (const int*)d_in[1 + 1 * 9 + 0];
  const int* d_src2 = (const int*)d_in[1 + 2 * 9 + 0];
  const float* d_ew0 = (const float*)d_in[1 + 0 * 9 + 2];
  const float* d_ew1 = (const float*)d_in[1 + 1 * 9 + 2];
  const float* d_ew2 = (const float*)d_in[1 + 2 * 9 + 2];

  // one-time conversions (independent of CSR build)
  convert_h_kernel<<<(N_ * 256 / 8 + 255) / 256, 256, 0, stream>>>(h, hf, N_ * 256 / 8);
  transpose_w_kernel<<<dim3(256, 4), 256, 0, stream>>>(
      (const float*)d_in[1 + 0 * 9 + 5], (const float*)d_in[1 + 1 * 9 + 5],
      (const float*)d_in[1 + 2 * 9 + 5], Wp, WT);
  f16* WpT = WT + (size_t)3 * 65536;

  // atomic-free CSR build (batched over etypes)
  hist_kernel<<<dim3(NB, 3), 256, 0, stream>>>(d_dst0, d_dst1, d_dst2, ghist, rank16);
  blockpfx_kernel<<<dim3((N_ + 255) / 256, 3), 256, 0, stream>>>(ghist, counts);
  scan_kernel<<<3, 1024, 0, stream>>>(counts, off, N_, E_);
  place_kernel<<<dim3(edge_blocks, 3), 256, 0, stream>>>(
      d_dst0, d_dst1, d_dst2, d_src0, d_src1, d_src2, d_ew0, d_ew1, d_ew2,
      off, ghist, rank16, csr_src, csr_ew);

  for (int et = 0; et < 3; ++et) {
    const int base = 1 + et * 9;
    const int* nbr_idx = (const int*)d_in[base + 3];
    const float* nbr_w = (const float*)d_in[base + 4];
    const float* al = (const float*)d_in[base + 6];
    const float* ar = (const float*)d_in[base + 7];
    const float* b = (const float*)d_in[base + 8];

    gemm_mfma<0><<<dim3(row_blocks, 4), 256, 0, stream>>>(
        hf, WT + (size_t)et * 65536, feat, nullptr, N_, al, ar, el, er,
        nullptr, nullptr, nullptr, nullptr, nullptr, 256, 0);

    aggregate_kernel<<<N_, 256, 0, stream>>>(
        off + (size_t)et * (N_ + 1), csr_src + (size_t)et * E_, csr_ew + (size_t)et * E_,
        el, er, (const __half*)feat, b, (__half*)gat);

    project_tb_kernel<<<wave_blocks, 256, 0, stream>>>(
        (const __half*)gat, Wt, Wb, gt, gb, N_);

    enhance_pool_kernel<<<wave_blocks, 256, 0, stream>>>(
        nbr_idx, nbr_w, gt, gb, bt, bb, tvec, bvec, N_);

    gemm_mfma<1><<<dim3(row_blocks, 4), 256, 0, stream>>>(
        gat, WpT, nullptr, out, N_, nullptr, nullptr, nullptr, nullptr,
        tvec, bvec, Wp + 256 * 256, Wp + 264 * 256, bp, 768, et * 256);
  }
}

// Round 7
// 612.177 us; speedup vs baseline: 3.1146x; 1.0507x over previous
//
#include <hip/hip_runtime.h>
#include <hip/hip_fp16.h>

#define N_NODES 30000
#define N_EDGES 480000
#define NB 16           // blocks per etype for counting sort
#define CHUNK 30000     // N_EDGES / NB

typedef _Float16 f16;
typedef f16 f16x8 __attribute__((ext_vector_type(8)));
typedef float f32x4 __attribute__((ext_vector_type(4)));

// ================= one-time converts =================
__global__ void convert_h_kernel(const float* __restrict__ in, f16* __restrict__ out, int n8)
{
  int i = blockIdx.x * 256 + threadIdx.x;
  if (i >= n8) return;
  float4 a = *(const float4*)(in + (size_t)i * 8);
  float4 b = *(const float4*)(in + (size_t)i * 8 + 4);
  f16x8 v;
  v[0] = (f16)a.x; v[1] = (f16)a.y; v[2] = (f16)a.z; v[3] = (f16)a.w;
  v[4] = (f16)b.x; v[5] = (f16)b.y; v[6] = (f16)b.z; v[7] = (f16)b.w;
  *(f16x8*)(out + (size_t)i * 8) = v;
}

// out[m][n][k] = (f16) in_m[k][n], 4 matrices 256x256, blockIdx.y = m
__global__ void transpose_w_kernel(const float* __restrict__ s0, const float* __restrict__ s1,
                                   const float* __restrict__ s2, const float* __restrict__ s3,
                                   f16* __restrict__ out)
{
  int m = blockIdx.y;
  const float* in = (m == 0) ? s0 : (m == 1) ? s1 : (m == 2) ? s2 : s3;
  int t = blockIdx.x * 256 + threadIdx.x;   // 65536
  int n = t >> 8, k = t & 255;
  out[(size_t)m * 65536 + t] = (f16)in[k * 256 + n];
}

// ================= MFMA GEMM: 128x64 tile, B-in-LDS-once, A direct from global =================
// MODE 0: feat(f16) = A@B; epilogue el/er (col-tile == head)
// MODE 1: out(f32) = A@B + t@Wp1 + bo@Wp2 + bp, strided store
template<int MODE>
__global__ __launch_bounds__(256)
void gemm_mfma(const f16* __restrict__ A, const f16* __restrict__ BT,
               f16* __restrict__ Ch, float* __restrict__ Cf, int M,
               const float* __restrict__ al, const float* __restrict__ ar,
               float* __restrict__ el, float* __restrict__ er,
               const float* __restrict__ tvec, const float* __restrict__ bvec,
               const float* __restrict__ Wp1, const float* __restrict__ Wp2,
               const float* __restrict__ bp, int ldc, int coff)
{
  __shared__ alignas(16) f16 Bs[64][264];   // +8 f16 pad
  __shared__ float W1s[8][64];
  __shared__ float W2s[8][64];
  __shared__ float t_lds[128][8];
  __shared__ float b_lds[128][8];

  const int tid = threadIdx.x;
  const int lane = tid & 63, wv = tid >> 6;
  const int l15 = lane & 15, lq = lane >> 4;
  const int bm = blockIdx.x * 128;
  const int ct = blockIdx.y;
  const int bn = ct * 64;

  // stage B col-tile ONCE: 64 cols x 256 k (each uint4 = 8 f16)
#pragma unroll
  for (int i = 0; i < 8; ++i) {
    int seg = tid + i * 256;        // 0..2047
    int row = seg >> 5;             // 0..63  (32 segments of 8 f16 per row)
    int cs = (seg & 31) * 8;        // 0..248
    *(uint4*)&Bs[row][cs] = *(const uint4*)&BT[(size_t)(bn + row) * 256 + cs];
  }

  if (MODE == 1) {
    if (tid < 128) {
      int r = tid >> 4, c4 = (tid & 15) * 4;
      *(float4*)&W1s[r][c4] = *(const float4*)&Wp1[r * 256 + bn + c4];
    } else {
      int t2 = tid - 128;
      int r = t2 >> 4, c4 = (t2 & 15) * 4;
      *(float4*)&W2s[r][c4] = *(const float4*)&Wp2[r * 256 + bn + c4];
    }
    {
      int r = tid >> 1, c = (tid & 1) * 4;
      int row = bm + r;
      float4 tv = make_float4(0.f, 0.f, 0.f, 0.f), bv2 = tv;
      if (row < M) {
        tv  = *(const float4*)&tvec[(size_t)row * 8 + c];
        bv2 = *(const float4*)&bvec[(size_t)row * 8 + c];
      }
      *(float4*)&t_lds[r][c] = tv;
      *(float4*)&b_lds[r][c] = bv2;
    }
  }
  __syncthreads();

  const int r0 = bm + wv * 32 + l15;
  const int r1 = r0 + 16;
  const bool ok0 = r0 < M, ok1 = r1 < M;
  const f16* Arow0 = A + (size_t)r0 * 256;
  const f16* Arow1 = A + (size_t)r1 * 256;

  f32x4 acc[2][4] = {};

#pragma unroll
  for (int k0 = 0; k0 < 256; k0 += 32) {
    int ko = k0 + lq * 8;
    f16x8 a0 = {0, 0, 0, 0, 0, 0, 0, 0};
    f16x8 a1 = {0, 0, 0, 0, 0, 0, 0, 0};
    if (ok0) a0 = *(const f16x8*)(Arow0 + ko);
    if (ok1) a1 = *(const f16x8*)(Arow1 + ko);
#pragma unroll
    for (int nf = 0; nf < 4; ++nf) {
      f16x8 bf = *(const f16x8*)&Bs[nf * 16 + l15][ko];
      acc[0][nf] = __builtin_amdgcn_mfma_f32_16x16x32_f16(a0, bf, acc[0][nf], 0, 0, 0);
      acc[1][nf] = __builtin_amdgcn_mfma_f32_16x16x32_f16(a1, bf, acc[1][nf], 0, 0, 0);
    }
  }

  if (MODE == 0) {
    float alv[4], arv[4];
#pragma unroll
    for (int nf = 0; nf < 4; ++nf) {
      alv[nf] = al[bn + nf * 16 + l15];
      arv[nf] = ar[bn + nf * 16 + l15];
    }
#pragma unroll
    for (int m = 0; m < 2; ++m)
#pragma unroll
      for (int i = 0; i < 4; ++i) {
        int row = bm + wv * 32 + m * 16 + lq * 4 + i;
        float pe = 0.f, pr = 0.f;
#pragma unroll
        for (int nf = 0; nf < 4; ++nf) {
          pe = fmaf(acc[m][nf][i], alv[nf], pe);
          pr = fmaf(acc[m][nf][i], arv[nf], pr);
        }
#pragma unroll
        for (int o = 8; o >= 1; o >>= 1) {
          pe += __shfl_xor(pe, o, 64);
          pr += __shfl_xor(pr, o, 64);
        }
        if (row < M) {
          if (l15 == 0) {
            el[row * 4 + ct] = pe;
            er[row * 4 + ct] = pr;
          }
#pragma unroll
          for (int nf = 0; nf < 4; ++nf)
            Ch[(size_t)row * 256 + bn + nf * 16 + l15] = (f16)acc[m][nf][i];
        }
      }
  } else {
    float bpv[4];
#pragma unroll
    for (int nf = 0; nf < 4; ++nf) bpv[nf] = bp[bn + nf * 16 + l15];
#pragma unroll
    for (int m = 0; m < 2; ++m)
#pragma unroll
      for (int i = 0; i < 4; ++i) {
        int rl = wv * 32 + m * 16 + lq * 4 + i;
        int row = bm + rl;
        if (row >= M) continue;
#pragma unroll
        for (int nf = 0; nf < 4; ++nf) {
          int c = nf * 16 + l15;
          float v = acc[m][nf][i] + bpv[nf];
#pragma unroll
          for (int k = 0; k < 8; ++k) {
            v = fmaf(t_lds[rl][k], W1s[k][c], v);
            v = fmaf(b_lds[rl][k], W2s[k][c], v);
          }
          Cf[(size_t)row * ldc + coff + bn + c] = v;
        }
      }
  }
}

// ============== CSR build pass 1: LDS histogram + per-edge local rank ==============
__global__ __launch_bounds__(256)
void hist_kernel(const int* __restrict__ d0, const int* __restrict__ d1,
                 const int* __restrict__ d2, int* __restrict__ ghist,
                 unsigned short* __restrict__ rank16)
{
  __shared__ unsigned int h32[N_NODES / 2];
  int et = blockIdx.y, b = blockIdx.x, tid = threadIdx.x;
  const int* dst = (et == 0) ? d0 : (et == 1) ? d1 : d2;
  for (int i = tid; i < N_NODES / 2; i += 256) h32[i] = 0u;
  __syncthreads();
  int e0 = b * CHUNK;
  for (int i = tid; i < CHUNK; i += 256) {
    int e = e0 + i;
    int d = dst[e];
    unsigned int sh = (d & 1) * 16;
    unsigned int old = atomicAdd(&h32[d >> 1], 1u << sh);
    rank16[(size_t)et * N_EDGES + e] = (unsigned short)((old >> sh) & 0xFFFFu);
  }
  __syncthreads();
  int* gh = ghist + ((size_t)(et * NB + b)) * N_NODES;
  for (int d = tid; d < N_NODES; d += 256)
    gh[d] = (int)((h32[d >> 1] >> ((d & 1) * 16)) & 0xFFFFu);
}

// ============== pass 2: per-dst exclusive prefix over NB blocks + totals ==============
__global__ __launch_bounds__(256)
void blockpfx_kernel(int* __restrict__ ghist, int* __restrict__ counts)
{
  int d = blockIdx.x * 256 + threadIdx.x;
  int et = blockIdx.y;
  if (d >= N_NODES) return;
  int running = 0;
#pragma unroll
  for (int b = 0; b < NB; ++b) {
    size_t idx = ((size_t)(et * NB + b)) * N_NODES + d;
    int v = ghist[idx];
    ghist[idx] = running;
    running += v;
  }
  counts[et * N_NODES + d] = running;
}

// ============== batched scan (blockIdx.x = etype) ==============
__global__ __launch_bounds__(1024)
void scan_kernel(int* __restrict__ cc_all, int* __restrict__ off_all, int n, int total)
{
  int et = blockIdx.x;
  int* cc = cc_all + (size_t)et * n;
  int* off = off_all + (size_t)et * (n + 1);
  __shared__ int wsum[16];
  __shared__ int woff[16];
  __shared__ int s_carry, s_chunk;
  int tid = threadIdx.x;
  int lane = tid & 63, wid = tid >> 6;
  if (tid == 0) s_carry = 0;
  __syncthreads();
  for (int base = 0; base < n; base += 1024) {
    int i = base + tid;
    int v = (i < n) ? cc[i] : 0;
    int x = v;
#pragma unroll
    for (int s = 1; s < 64; s <<= 1) {
      int y = __shfl_up(x, s, 64);
      if (lane >= s) x += y;
    }
    if (lane == 63) wsum[wid] = x;
    __syncthreads();
    if (wid == 0 && lane < 16) {
      int ws_ = wsum[lane];
      int xx = ws_;
#pragma unroll
      for (int s = 1; s < 16; s <<= 1) {
        int y = __shfl_up(xx, s, 64);
        if (lane >= s) xx += y;
      }
      woff[lane] = xx - ws_;
      if (lane == 15) s_chunk = xx;
    }
    __syncthreads();
    int excl = s_carry + woff[wid] + (x - v);
    if (i < n) { off[i] = excl; cc[i] = excl; }
    __syncthreads();
    if (tid == 0) s_carry += s_chunk;
    __syncthreads();
  }
  if (tid == 0) off[n] = total;
}

// ============== pass 4: place packed payload (no atomics, single 8B scatter) ==============
__global__ __launch_bounds__(256)
void place_kernel(const int* __restrict__ d0, const int* __restrict__ d1,
                  const int* __restrict__ d2,
                  const int* __restrict__ s0, const int* __restrict__ s1,
                  const int* __restrict__ s2,
                  const float* __restrict__ w0, const float* __restrict__ w1,
                  const float* __restrict__ w2,
                  const int* __restrict__ off, const int* __restrict__ ghist,
                  const unsigned short* __restrict__ rank16,
                  int2* __restrict__ csr_pay)
{
  int e = blockIdx.x * 256 + threadIdx.x;
  if (e >= N_EDGES) return;
  int et = blockIdx.y;
  const int* dst = (et == 0) ? d0 : (et == 1) ? d1 : d2;
  const int* src = (et == 0) ? s0 : (et == 1) ? s1 : s2;
  const float* ew = (et == 0) ? w0 : (et == 1) ? w1 : w2;
  int d = dst[e];
  int b = e / CHUNK;
  int pos = off[et * (N_NODES + 1) + d]
          + ghist[((size_t)(et * NB + b)) * N_NODES + d]
          + (int)rank16[(size_t)et * N_EDGES + e];
  csr_pay[(size_t)et * N_EDGES + pos] = make_int2(src[e], __float_as_int(ew[e]));
}

// ============== per-dst aggregation (softmax in-block, atomic-free) ==============
__global__ __launch_bounds__(256)
void aggregate_kernel(const int* __restrict__ off, const int2* __restrict__ csr_pay,
                      const float* __restrict__ el, const float* __restrict__ er,
                      const __half* __restrict__ feat, const float* __restrict__ bias,
                      __half* __restrict__ gat)
{
  int n = blockIdx.x;
  int tid = threadIdx.x;
  int lane = tid & 63, wv = tid >> 6;
  int hd = lane >> 4;                    // head of this lane's 4-column slice
  __shared__ int s_src[256];
  __shared__ float s_coef[256][4];       // ex * ew
  __shared__ float s_ex[256][4];         // ex (for denom)
  __shared__ float red[4][256];
  __shared__ float sdn[4];
  int e0 = off[n], e1 = off[n + 1];
  float4 er4 = *(const float4*)&er[(size_t)n * 4];
  if (tid < 4) sdn[tid] = 0.f;
  float ac0 = 0.f, ac1 = 0.f, ac2 = 0.f, ac3 = 0.f;

  for (int base = e0; base < e1; base += 256) {
    int cnt = min(256, e1 - base);
    __syncthreads();
    if (tid < cnt) {
      int2 pay = csr_pay[base + tid];
      int s = pay.x;
      float w = __int_as_float(pay.y);
      s_src[tid] = s;
      float4 l4 = *(const float4*)&el[(size_t)s * 4];
      float v0 = l4.x + er4.x; v0 = v0 > 0.f ? v0 : 0.2f * v0;
      float v1 = l4.y + er4.y; v1 = v1 > 0.f ? v1 : 0.2f * v1;
      float v2 = l4.z + er4.z; v2 = v2 > 0.f ? v2 : 0.2f * v2;
      float v3 = l4.w + er4.w; v3 = v3 > 0.f ? v3 : 0.2f * v3;
      float x0 = __expf(v0), x1 = __expf(v1), x2 = __expf(v2), x3 = __expf(v3);
      s_ex[tid][0] = x0; s_ex[tid][1] = x1; s_ex[tid][2] = x2; s_ex[tid][3] = x3;
      s_coef[tid][0] = x0 * w; s_coef[tid][1] = x1 * w;
      s_coef[tid][2] = x2 * w; s_coef[tid][3] = x3 * w;
    }
    __syncthreads();
    if (wv == 0) {
      float p = 0.f;
      for (int k = lane >> 2; k < cnt; k += 16) p += s_ex[k][lane & 3];
      p += __shfl_xor(p, 4, 64);
      p += __shfl_xor(p, 8, 64);
      p += __shfl_xor(p, 16, 64);
      p += __shfl_xor(p, 32, 64);
      if (lane < 4) sdn[lane] += p;
    }
    int k = wv;
    for (; k + 12 < cnt; k += 16) {
      int sA = s_src[k], sB = s_src[k + 4], sC = s_src[k + 8], sD = s_src[k + 12];
      float cA = s_coef[k][hd];
      float cB = s_coef[k + 4][hd];
      float cC = s_coef[k + 8][hd];
      float cD = s_coef[k + 12][hd];
      uint2 uA = *(const uint2*)(feat + (size_t)sA * 256 + lane * 4);
      uint2 uB = *(const uint2*)(feat + (size_t)sB * 256 + lane * 4);
      uint2 uC = *(const uint2*)(feat + (size_t)sC * 256 + lane * 4);
      uint2 uD = *(const uint2*)(feat + (size_t)sD * 256 + lane * 4);
      float2 A01 = __half22float2(*(__half2*)&uA.x), A23 = __half22float2(*(__half2*)&uA.y);
      float2 B01 = __half22float2(*(__half2*)&uB.x), B23 = __half22float2(*(__half2*)&uB.y);
      float2 C01 = __half22float2(*(__half2*)&uC.x), C23 = __half22float2(*(__half2*)&uC.y);
      float2 D01 = __half22float2(*(__half2*)&uD.x), D23 = __half22float2(*(__half2*)&uD.y);
      ac0 = fmaf(cA, A01.x, ac0); ac1 = fmaf(cA, A01.y, ac1);
      ac2 = fmaf(cA, A23.x, ac2); ac3 = fmaf(cA, A23.y, ac3);
      ac0 = fmaf(cB, B01.x, ac0); ac1 = fmaf(cB, B01.y, ac1);
      ac2 = fmaf(cB, B23.x, ac2); ac3 = fmaf(cB, B23.y, ac3);
      ac0 = fmaf(cC, C01.x, ac0); ac1 = fmaf(cC, C01.y, ac1);
      ac2 = fmaf(cC, C23.x, ac2); ac3 = fmaf(cC, C23.y, ac3);
      ac0 = fmaf(cD, D01.x, ac0); ac1 = fmaf(cD, D01.y, ac1);
      ac2 = fmaf(cD, D23.x, ac2); ac3 = fmaf(cD, D23.y, ac3);
    }
    for (; k < cnt; k += 4) {
      int s0 = s_src[k];
      float c0 = s_coef[k][hd];
      uint2 u = *(const uint2*)(feat + (size_t)s0 * 256 + lane * 4);
      float2 f01 = __half22float2(*(__half2*)&u.x), f23 = __half22float2(*(__half2*)&u.y);
      ac0 = fmaf(c0, f01.x, ac0); ac1 = fmaf(c0, f01.y, ac1);
      ac2 = fmaf(c0, f23.x, ac2); ac3 = fmaf(c0, f23.y, ac3);
    }
  }
  red[wv][lane * 4 + 0] = ac0;
  red[wv][lane * 4 + 1] = ac1;
  red[wv][lane * 4 + 2] = ac2;
  red[wv][lane * 4 + 3] = ac3;
  __syncthreads();
  float dn = sdn[tid >> 6];
  float invd = (dn != 0.f) ? 1.f / dn : 0.f;
  float v = (red[0][tid] + red[1][tid] + red[2][tid] + red[3][tid]) * invd + bias[tid];
  gat[(size_t)n * 256 + tid] = __float2half_rn(v);
}

// ============== gt = gat@Wt, gb = gat@Wb  ([N,8] each, f32) ==============
__global__ __launch_bounds__(256)
void project_tb_kernel(const __half* __restrict__ gat,
                       const float* __restrict__ Wt, const float* __restrict__ Wb,
                       float* __restrict__ gt, float* __restrict__ gb, int n_nodes)
{
  int node = (blockIdx.x * 256 + threadIdx.x) >> 6;
  int lane = threadIdx.x & 63;
  if (node >= n_nodes) return;
  uint2 u = *(const uint2*)(gat + (size_t)node * 256 + lane * 4);
  float2 f01 = __half22float2(*(__half2*)&u.x);
  float2 f23 = __half22float2(*(__half2*)&u.y);
  float f[4] = {f01.x, f01.y, f23.x, f23.y};
  float p[16];
#pragma unroll
  for (int j = 0; j < 16; ++j) p[j] = 0.f;
#pragma unroll
  for (int r = 0; r < 4; ++r) {
    int c = lane * 4 + r;
    const float* wtr = &Wt[(size_t)c * 8];
    const float* wbr = &Wb[(size_t)c * 8];
#pragma unroll
    for (int j = 0; j < 8; ++j) {
      p[j]     = fmaf(f[r], wtr[j], p[j]);
      p[8 + j] = fmaf(f[r], wbr[j], p[8 + j]);
    }
  }
#pragma unroll
  for (int o = 32; o >= 1; o >>= 1) {
#pragma unroll
    for (int j = 0; j < 16; ++j) p[j] += __shfl_xor(p[j], o, 64);
  }
  if (lane == 0) {
    *(float4*)&gt[(size_t)node * 8]     = make_float4(p[0], p[1], p[2], p[3]);
    *(float4*)&gt[(size_t)node * 8 + 4] = make_float4(p[4], p[5], p[6], p[7]);
    *(float4*)&gb[(size_t)node * 8]     = make_float4(p[8], p[9], p[10], p[11]);
    *(float4*)&gb[(size_t)node * 8 + 4] = make_float4(p[12], p[13], p[14], p[15]);
  }
}

// ============== enhance: wave-per-node; rank + tiny gt/gb gathers ==============
__global__ __launch_bounds__(256)
void enhance_pool_kernel(const int* __restrict__ nbr_idx, const float* __restrict__ nbr_w,
                         const float* __restrict__ gt, const float* __restrict__ gb,
                         const float* __restrict__ bt, const float* __restrict__ bb,
                         float* __restrict__ tvec, float* __restrict__ bvec, int n_nodes)
{
  int n = (blockIdx.x * 256 + threadIdx.x) >> 6;
  int lane = threadIdx.x & 63;
  if (n >= n_nodes) return;
  const int l16 = lane & 15;

  float w = nbr_w[(size_t)n * 16 + l16];
  int idx = nbr_idx[(size_t)n * 16 + l16];

  int rhi = 0, rlo = 0;
#pragma unroll
  for (int i = 0; i < 16; ++i) {
    float wi = __shfl(w, i, 64);
    rhi += (wi > w) || (wi == w && i < l16);
    rlo += (wi < w) || (wi == w && i < l16);
  }

  int rows[7];
#pragma unroll
  for (int q = 0; q < 5; ++q) {
    unsigned long long m = __ballot(lane < 16 && rhi == q);
    rows[q] = __shfl(idx, __ffsll(m) - 1, 64);
  }
#pragma unroll
  for (int q = 0; q < 2; ++q) {
    unsigned long long m = __ballot(lane < 16 && rlo == q);
    rows[5 + q] = __shfl(idx, __ffsll(m) - 1, 64);
  }

  int j = lane & 7;
  if (lane < 8) {
    float s = 0.f;
#pragma unroll
    for (int q = 0; q < 5; ++q) s += gt[(size_t)rows[q] * 8 + j];
    tvec[(size_t)n * 8 + j] = s * 0.2f + bt[j];
  } else if (lane < 16) {
    float s = gb[(size_t)rows[5] * 8 + j] + gb[(size_t)rows[6] * 8 + j];
    bvec[(size_t)n * 8 + j] = s * 0.5f + bb[j];
  }
}

extern "C" void kernel_launch(void* const* d_in, const int* in_sizes, int n_in,
                              void* d_out, int out_size, void* d_ws, size_t ws_size,
                              hipStream_t stream)
{
  const int N_ = N_NODES;
  const int E_ = N_EDGES;

  const float* h = (const float*)d_in[0];
  const float* Wt = (const float*)d_in[28];
  const float* bt = (const float*)d_in[29];
  const float* Wb = (const float*)d_in[30];
  const float* bb = (const float*)d_in[31];
  const float* Wp = (const float*)d_in[32];
  const float* bp = (const float*)d_in[33];
  float* out = (float*)d_out;

  char* wsb = (char*)d_ws;
  size_t o = 0;
  auto alloc = [&](size_t bytes) -> void* {
    void* p = wsb + o;
    o = (o + bytes + 255) & ~(size_t)255;
    return p;
  };
  f16*  hf    = (f16*)alloc((size_t)N_ * 256 * 2);
  f16*  feat  = (f16*)alloc((size_t)N_ * 256 * 2);
  f16*  gat   = (f16*)alloc((size_t)N_ * 256 * 2);
  f16*  WT    = (f16*)alloc((size_t)4 * 256 * 256 * 2);   // 3x W + WpT
  float* el     = (float*)alloc((size_t)N_ * 4 * 4);
  float* er     = (float*)alloc((size_t)N_ * 4 * 4);
  float* gt     = (float*)alloc((size_t)N_ * 8 * 4);
  float* gb     = (float*)alloc((size_t)N_ * 8 * 4);
  float* tvec   = (float*)alloc((size_t)N_ * 8 * 4);
  float* bvec   = (float*)alloc((size_t)N_ * 8 * 4);
  int*   off    = (int*)alloc((size_t)3 * (N_ + 1) * 4);
  int*   counts = (int*)alloc((size_t)3 * N_ * 4);
  int*   ghist  = (int*)alloc((size_t)3 * NB * N_ * 4);          // 5.76 MB
  unsigned short* rank16 = (unsigned short*)alloc((size_t)3 * E_ * 2);
  int2*  csr_pay = (int2*)alloc((size_t)3 * E_ * 8);
  (void)ws_size; (void)in_sizes; (void)n_in; (void)out_size;

  const int row_blocks = (N_ + 127) / 128;  // 235
  const int edge_blocks = (E_ + 255) / 256; // 1875
  const int wave_blocks = (N_ + 3) / 4;     // 7500

  const int* d_dst0 = (const int*)d_in[1 + 0 * 9 + 1];
  const int* d_dst1 = (const int*)d_in[1 + 1 * 9 + 1];
  const int* d_dst2 = (const int*)d_in[1 + 2 * 9 + 1];
  const int* d_src0 = (const int*)d_in[1 + 0 * 9 + 0];
  const int* d_src1 = (const int*)d_in[1 + 1 * 9 + 0];
  const int* d_src2 = (const int*)d_in[1 + 2 * 9 + 0];
  const float* d_ew0 = (const float*)d_in[1 + 0 * 9 + 2];
  const float* d_ew1 = (const float*)d_in[1 + 1 * 9 + 2];
  const float* d_ew2 = (const float*)d_in[1 + 2 * 9 + 2];

  // one-time conversions (independent of CSR build)
  convert_h_kernel<<<(N_ * 256 / 8 + 255) / 256, 256, 0, stream>>>(h, hf, N_ * 256 / 8);
  transpose_w_kernel<<<dim3(256, 4), 256, 0, stream>>>(
      (const float*)d_in[1 + 0 * 9 + 5], (const float*)d_in[1 + 1 * 9 + 5],
      (const float*)d_in[1 + 2 * 9 + 5], Wp, WT);
  f16* WpT = WT + (size_t)3 * 65536;

  // atomic-free CSR build (batched over etypes)
  hist_kernel<<<dim3(NB, 3), 256, 0, stream>>>(d_dst0, d_dst1, d_dst2, ghist, rank16);
  blockpfx_kernel<<<dim3((N_ + 255) / 256, 3), 256, 0, stream>>>(ghist, counts);
  scan_kernel<<<3, 1024, 0, stream>>>(counts, off, N_, E_);
  place_kernel<<<dim3(edge_blocks, 3), 256, 0, stream>>>(
      d_dst0, d_dst1, d_dst2, d_src0, d_src1, d_src2, d_ew0, d_ew1, d_ew2,
      off, ghist, rank16, csr_pay);

  for (int et = 0; et < 3; ++et) {
    const int base = 1 + et * 9;
    const int* nbr_idx = (const int*)d_in[base + 3];
    const float* nbr_w = (const float*)d_in[base + 4];
    const float* al = (const float*)d_in[base + 6];
    const float* ar = (const float*)d_in[base + 7];
    const float* b = (const float*)d_in[base + 8];

    gemm_mfma<0><<<dim3(row_blocks, 4), 256, 0, stream>>>(
        hf, WT + (size_t)et * 65536, feat, nullptr, N_, al, ar, el, er,
        nullptr, nullptr, nullptr, nullptr, nullptr, 256, 0);

    aggregate_kernel<<<N_, 256, 0, stream>>>(
        off + (size_t)et * (N_ + 1), csr_pay + (size_t)et * E_,
        el, er, (const __half*)feat, b, (__half*)gat);

    project_tb_kernel<<<wave_blocks, 256, 0, stream>>>(
        (const __half*)gat, Wt, Wb, gt, gb, N_);

    enhance_pool_kernel<<<wave_blocks, 256, 0, stream>>>(
        nbr_idx, nbr_w, gt, gb, bt, bb, tvec, bvec, N_);

    gemm_mfma<1><<<dim3(row_blocks, 4), 256, 0, stream>>>(
        gat, WpT, nullptr, out, N_, nullptr, nullptr, nullptr, nullptr,
        tvec, bvec, Wp + 256 * 256, Wp + 264 * 256, bp, 768, et * 256);
  }
}

// Round 8
// 540.736 us; speedup vs baseline: 3.5261x; 1.1321x over previous
//
#include <hip/hip_runtime.h>
#include <hip/hip_fp16.h>

#define N_NODES 30000
#define N_EDGES 480000
#define NB 64           // blocks per etype for counting sort
#define CHUNK 7500      // N_EDGES / NB  (< 65536 so u16 ranks/counts are safe)

typedef _Float16 f16;
typedef f16 f16x8 __attribute__((ext_vector_type(8)));
typedef float f32x4 __attribute__((ext_vector_type(4)));

// ================= one-time converts =================
__global__ void convert_h_kernel(const float* __restrict__ in, f16* __restrict__ out, int n8)
{
  int i = blockIdx.x * 256 + threadIdx.x;
  if (i >= n8) return;
  float4 a = *(const float4*)(in + (size_t)i * 8);
  float4 b = *(const float4*)(in + (size_t)i * 8 + 4);
  f16x8 v;
  v[0] = (f16)a.x; v[1] = (f16)a.y; v[2] = (f16)a.z; v[3] = (f16)a.w;
  v[4] = (f16)b.x; v[5] = (f16)b.y; v[6] = (f16)b.z; v[7] = (f16)b.w;
  *(f16x8*)(out + (size_t)i * 8) = v;
}

// out[m][n][k] = (f16) in_m[k][n], 4 matrices 256x256, blockIdx.y = m
__global__ void transpose_w_kernel(const float* __restrict__ s0, const float* __restrict__ s1,
                                   const float* __restrict__ s2, const float* __restrict__ s3,
                                   f16* __restrict__ out)
{
  int m = blockIdx.y;
  const float* in = (m == 0) ? s0 : (m == 1) ? s1 : (m == 2) ? s2 : s3;
  int t = blockIdx.x * 256 + threadIdx.x;   // 65536
  int n = t >> 8, k = t & 255;
  out[(size_t)m * 65536 + t] = (f16)in[k * 256 + n];
}

// ================= MFMA GEMM: 128x64 tile, B-in-LDS-once, A direct from global =================
// MODE 0: feat(f16) = A@B; epilogue el/er (col-tile == head)
// MODE 1: out(f32) = A@B + t@Wp1 + bo@Wp2 + bp, strided store
template<int MODE>
__global__ __launch_bounds__(256)
void gemm_mfma(const f16* __restrict__ A, const f16* __restrict__ BT,
               f16* __restrict__ Ch, float* __restrict__ Cf, int M,
               const float* __restrict__ al, const float* __restrict__ ar,
               float* __restrict__ el, float* __restrict__ er,
               const float* __restrict__ tvec, const float* __restrict__ bvec,
               const float* __restrict__ Wp1, const float* __restrict__ Wp2,
               const float* __restrict__ bp, int ldc, int coff)
{
  __shared__ alignas(16) f16 Bs[64][264];   // +8 f16 pad
  __shared__ float W1s[8][64];
  __shared__ float W2s[8][64];
  __shared__ float t_lds[128][8];
  __shared__ float b_lds[128][8];

  const int tid = threadIdx.x;
  const int lane = tid & 63, wv = tid >> 6;
  const int l15 = lane & 15, lq = lane >> 4;
  const int bm = blockIdx.x * 128;
  const int ct = blockIdx.y;
  const int bn = ct * 64;

  // stage B col-tile ONCE: 64 cols x 256 k (each uint4 = 8 f16)
#pragma unroll
  for (int i = 0; i < 8; ++i) {
    int seg = tid + i * 256;        // 0..2047
    int row = seg >> 5;             // 0..63  (32 segments of 8 f16 per row)
    int cs = (seg & 31) * 8;        // 0..248
    *(uint4*)&Bs[row][cs] = *(const uint4*)&BT[(size_t)(bn + row) * 256 + cs];
  }

  if (MODE == 1) {
    if (tid < 128) {
      int r = tid >> 4, c4 = (tid & 15) * 4;
      *(float4*)&W1s[r][c4] = *(const float4*)&Wp1[r * 256 + bn + c4];
    } else {
      int t2 = tid - 128;
      int r = t2 >> 4, c4 = (t2 & 15) * 4;
      *(float4*)&W2s[r][c4] = *(const float4*)&Wp2[r * 256 + bn + c4];
    }
    {
      int r = tid >> 1, c = (tid & 1) * 4;
      int row = bm + r;
      float4 tv = make_float4(0.f, 0.f, 0.f, 0.f), bv2 = tv;
      if (row < M) {
        tv  = *(const float4*)&tvec[(size_t)row * 8 + c];
        bv2 = *(const float4*)&bvec[(size_t)row * 8 + c];
      }
      *(float4*)&t_lds[r][c] = tv;
      *(float4*)&b_lds[r][c] = bv2;
    }
  }
  __syncthreads();

  const int r0 = bm + wv * 32 + l15;
  const int r1 = r0 + 16;
  const bool ok0 = r0 < M, ok1 = r1 < M;
  const f16* Arow0 = A + (size_t)r0 * 256;
  const f16* Arow1 = A + (size_t)r1 * 256;

  f32x4 acc[2][4] = {};

#pragma unroll
  for (int k0 = 0; k0 < 256; k0 += 32) {
    int ko = k0 + lq * 8;
    f16x8 a0 = {0, 0, 0, 0, 0, 0, 0, 0};
    f16x8 a1 = {0, 0, 0, 0, 0, 0, 0, 0};
    if (ok0) a0 = *(const f16x8*)(Arow0 + ko);
    if (ok1) a1 = *(const f16x8*)(Arow1 + ko);
#pragma unroll
    for (int nf = 0; nf < 4; ++nf) {
      f16x8 bf = *(const f16x8*)&Bs[nf * 16 + l15][ko];
      acc[0][nf] = __builtin_amdgcn_mfma_f32_16x16x32_f16(a0, bf, acc[0][nf], 0, 0, 0);
      acc[1][nf] = __builtin_amdgcn_mfma_f32_16x16x32_f16(a1, bf, acc[1][nf], 0, 0, 0);
    }
  }

  if (MODE == 0) {
    float alv[4], arv[4];
#pragma unroll
    for (int nf = 0; nf < 4; ++nf) {
      alv[nf] = al[bn + nf * 16 + l15];
      arv[nf] = ar[bn + nf * 16 + l15];
    }
#pragma unroll
    for (int m = 0; m < 2; ++m)
#pragma unroll
      for (int i = 0; i < 4; ++i) {
        int row = bm + wv * 32 + m * 16 + lq * 4 + i;
        float pe = 0.f, pr = 0.f;
#pragma unroll
        for (int nf = 0; nf < 4; ++nf) {
          pe = fmaf(acc[m][nf][i], alv[nf], pe);
          pr = fmaf(acc[m][nf][i], arv[nf], pr);
        }
#pragma unroll
        for (int o = 8; o >= 1; o >>= 1) {
          pe += __shfl_xor(pe, o, 64);
          pr += __shfl_xor(pr, o, 64);
        }
        if (row < M) {
          if (l15 == 0) {
            el[row * 4 + ct] = pe;
            er[row * 4 + ct] = pr;
          }
#pragma unroll
          for (int nf = 0; nf < 4; ++nf)
            Ch[(size_t)row * 256 + bn + nf * 16 + l15] = (f16)acc[m][nf][i];
        }
      }
  } else {
    float bpv[4];
#pragma unroll
    for (int nf = 0; nf < 4; ++nf) bpv[nf] = bp[bn + nf * 16 + l15];
#pragma unroll
    for (int m = 0; m < 2; ++m)
#pragma unroll
      for (int i = 0; i < 4; ++i) {
        int rl = wv * 32 + m * 16 + lq * 4 + i;
        int row = bm + rl;
        if (row >= M) continue;
#pragma unroll
        for (int nf = 0; nf < 4; ++nf) {
          int c = nf * 16 + l15;
          float v = acc[m][nf][i] + bpv[nf];
#pragma unroll
          for (int k = 0; k < 8; ++k) {
            v = fmaf(t_lds[rl][k], W1s[k][c], v);
            v = fmaf(b_lds[rl][k], W2s[k][c], v);
          }
          Cf[(size_t)row * ldc + coff + bn + c] = v;
        }
      }
  }
}

// ============== CSR build pass 1: LDS histogram + per-edge local rank ==============
// grid (NB, 3), 512 threads. hist packed 2 x u16 per u32 (count <= CHUNK < 65536).
__global__ __launch_bounds__(512)
void hist_kernel(const int* __restrict__ d0, const int* __restrict__ d1,
                 const int* __restrict__ d2, unsigned short* __restrict__ ghist,
                 unsigned short* __restrict__ rank16)
{
  __shared__ unsigned int h32[N_NODES / 2];
  int et = blockIdx.y, b = blockIdx.x, tid = threadIdx.x;
  const int* dst = (et == 0) ? d0 : (et == 1) ? d1 : d2;
  for (int i = tid; i < N_NODES / 2; i += 512) h32[i] = 0u;
  __syncthreads();
  int e0 = b * CHUNK;
  for (int i = tid; i < CHUNK; i += 512) {
    int e = e0 + i;
    int d = dst[e];
    unsigned int sh = (d & 1) * 16;
    unsigned int old = atomicAdd(&h32[d >> 1], 1u << sh);
    rank16[(size_t)et * N_EDGES + e] = (unsigned short)((old >> sh) & 0xFFFFu);
  }
  __syncthreads();
  unsigned short* gh = ghist + ((size_t)(et * NB + b)) * N_NODES;
  for (int d = tid; d < N_NODES; d += 512)
    gh[d] = (unsigned short)((h32[d >> 1] >> ((d & 1) * 16)) & 0xFFFFu);
}

// ============== pass 2: per-dst exclusive prefix over NB blocks + totals ==============
__global__ __launch_bounds__(256)
void blockpfx_kernel(unsigned short* __restrict__ ghist, int* __restrict__ counts)
{
  int d = blockIdx.x * 256 + threadIdx.x;
  int et = blockIdx.y;
  if (d >= N_NODES) return;
  int running = 0;
#pragma unroll
  for (int b = 0; b < NB; ++b) {
    size_t idx = ((size_t)(et * NB + b)) * N_NODES + d;
    int v = ghist[idx];
    ghist[idx] = (unsigned short)running;   // per-dst degree << 65536
    running += v;
  }
  counts[et * N_NODES + d] = running;
}

// ============== batched scan (blockIdx.x = etype) ==============
__global__ __launch_bounds__(1024)
void scan_kernel(int* __restrict__ cc_all, int* __restrict__ off_all, int n, int total)
{
  int et = blockIdx.x;
  int* cc = cc_all + (size_t)et * n;
  int* off = off_all + (size_t)et * (n + 1);
  __shared__ int wsum[16];
  __shared__ int woff[16];
  __shared__ int s_carry, s_chunk;
  int tid = threadIdx.x;
  int lane = tid & 63, wid = tid >> 6;
  if (tid == 0) s_carry = 0;
  __syncthreads();
  for (int base = 0; base < n; base += 1024) {
    int i = base + tid;
    int v = (i < n) ? cc[i] : 0;
    int x = v;
#pragma unroll
    for (int s = 1; s < 64; s <<= 1) {
      int y = __shfl_up(x, s, 64);
      if (lane >= s) x += y;
    }
    if (lane == 63) wsum[wid] = x;
    __syncthreads();
    if (wid == 0 && lane < 16) {
      int ws_ = wsum[lane];
      int xx = ws_;
#pragma unroll
      for (int s = 1; s < 16; s <<= 1) {
        int y = __shfl_up(xx, s, 64);
        if (lane >= s) xx += y;
      }
      woff[lane] = xx - ws_;
      if (lane == 15) s_chunk = xx;
    }
    __syncthreads();
    int excl = s_carry + woff[wid] + (x - v);
    if (i < n) { off[i] = excl; cc[i] = excl; }
    __syncthreads();
    if (tid == 0) s_carry += s_chunk;
    __syncthreads();
  }
  if (tid == 0) off[n] = total;
}

// ============== pass 4: place packed payload (no atomics, single 8B scatter) ==============
__global__ __launch_bounds__(256)
void place_kernel(const int* __restrict__ d0, const int* __restrict__ d1,
                  const int* __restrict__ d2,
                  const int* __restrict__ s0, const int* __restrict__ s1,
                  const int* __restrict__ s2,
                  const float* __restrict__ w0, const float* __restrict__ w1,
                  const float* __restrict__ w2,
                  const int* __restrict__ off, const unsigned short* __restrict__ ghist,
                  const unsigned short* __restrict__ rank16,
                  int2* __restrict__ csr_pay)
{
  int e = blockIdx.x * 256 + threadIdx.x;
  if (e >= N_EDGES) return;
  int et = blockIdx.y;
  const int* dst = (et == 0) ? d0 : (et == 1) ? d1 : d2;
  const int* src = (et == 0) ? s0 : (et == 1) ? s1 : s2;
  const float* ew = (et == 0) ? w0 : (et == 1) ? w1 : w2;
  int d = dst[e];
  int b = e / CHUNK;
  int pos = off[et * (N_NODES + 1) + d]
          + (int)ghist[((size_t)(et * NB + b)) * N_NODES + d]
          + (int)rank16[(size_t)et * N_EDGES + e];
  csr_pay[(size_t)et * N_EDGES + pos] = make_int2(src[e], __float_as_int(ew[e]));
}

// ============== per-dst aggregation (softmax in-block) + fused gt/gb projection ==============
__global__ __launch_bounds__(256)
void aggregate_kernel(const int* __restrict__ off, const int2* __restrict__ csr_pay,
                      const float* __restrict__ el, const float* __restrict__ er,
                      const __half* __restrict__ feat, const float* __restrict__ bias,
                      const float* __restrict__ Wt, const float* __restrict__ Wb,
                      __half* __restrict__ gat, float* __restrict__ gt, float* __restrict__ gb)
{
  int n = blockIdx.x;
  int tid = threadIdx.x;
  int lane = tid & 63, wv = tid >> 6;
  int hd = lane >> 4;                    // head of this lane's 4-column slice
  __shared__ int s_src[256];
  __shared__ float s_coef[256][4];       // ex * ew
  __shared__ float s_ex[256][4];         // ex (for denom)
  __shared__ float red[4][256];
  __shared__ float sdn[4];
  __shared__ float vbuf[256];
  int e0 = off[n], e1 = off[n + 1];
  float4 er4 = *(const float4*)&er[(size_t)n * 4];
  if (tid < 4) sdn[tid] = 0.f;
  float ac0 = 0.f, ac1 = 0.f, ac2 = 0.f, ac3 = 0.f;

  for (int base = e0; base < e1; base += 256) {
    int cnt = min(256, e1 - base);
    __syncthreads();
    if (tid < cnt) {
      int2 pay = csr_pay[base + tid];
      int s = pay.x;
      float w = __int_as_float(pay.y);
      s_src[tid] = s;
      float4 l4 = *(const float4*)&el[(size_t)s * 4];
      float v0 = l4.x + er4.x; v0 = v0 > 0.f ? v0 : 0.2f * v0;
      float v1 = l4.y + er4.y; v1 = v1 > 0.f ? v1 : 0.2f * v1;
      float v2 = l4.z + er4.z; v2 = v2 > 0.f ? v2 : 0.2f * v2;
      float v3 = l4.w + er4.w; v3 = v3 > 0.f ? v3 : 0.2f * v3;
      float x0 = __expf(v0), x1 = __expf(v1), x2 = __expf(v2), x3 = __expf(v3);
      s_ex[tid][0] = x0; s_ex[tid][1] = x1; s_ex[tid][2] = x2; s_ex[tid][3] = x3;
      s_coef[tid][0] = x0 * w; s_coef[tid][1] = x1 * w;
      s_coef[tid][2] = x2 * w; s_coef[tid][3] = x3 * w;
    }
    __syncthreads();
    if (wv == 0) {
      float p = 0.f;
      for (int k = lane >> 2; k < cnt; k += 16) p += s_ex[k][lane & 3];
      p += __shfl_xor(p, 4, 64);
      p += __shfl_xor(p, 8, 64);
      p += __shfl_xor(p, 16, 64);
      p += __shfl_xor(p, 32, 64);
      if (lane < 4) sdn[lane] += p;
    }
    int k = wv;
    for (; k + 12 < cnt; k += 16) {
      int sA = s_src[k], sB = s_src[k + 4], sC = s_src[k + 8], sD = s_src[k + 12];
      float cA = s_coef[k][hd];
      float cB = s_coef[k + 4][hd];
      float cC = s_coef[k + 8][hd];
      float cD = s_coef[k + 12][hd];
      uint2 uA = *(const uint2*)(feat + (size_t)sA * 256 + lane * 4);
      uint2 uB = *(const uint2*)(feat + (size_t)sB * 256 + lane * 4);
      uint2 uC = *(const uint2*)(feat + (size_t)sC * 256 + lane * 4);
      uint2 uD = *(const uint2*)(feat + (size_t)sD * 256 + lane * 4);
      float2 A01 = __half22float2(*(__half2*)&uA.x), A23 = __half22float2(*(__half2*)&uA.y);
      float2 B01 = __half22float2(*(__half2*)&uB.x), B23 = __half22float2(*(__half2*)&uB.y);
      float2 C01 = __half22float2(*(__half2*)&uC.x), C23 = __half22float2(*(__half2*)&uC.y);
      float2 D01 = __half22float2(*(__half2*)&uD.x), D23 = __half22float2(*(__half2*)&uD.y);
      ac0 = fmaf(cA, A01.x, ac0); ac1 = fmaf(cA, A01.y, ac1);
      ac2 = fmaf(cA, A23.x, ac2); ac3 = fmaf(cA, A23.y, ac3);
      ac0 = fmaf(cB, B01.x, ac0); ac1 = fmaf(cB, B01.y, ac1);
      ac2 = fmaf(cB, B23.x, ac2); ac3 = fmaf(cB, B23.y, ac3);
      ac0 = fmaf(cC, C01.x, ac0); ac1 = fmaf(cC, C01.y, ac1);
      ac2 = fmaf(cC, C23.x, ac2); ac3 = fmaf(cC, C23.y, ac3);
      ac0 = fmaf(cD, D01.x, ac0); ac1 = fmaf(cD, D01.y, ac1);
      ac2 = fmaf(cD, D23.x, ac2); ac3 = fmaf(cD, D23.y, ac3);
    }
    for (; k < cnt; k += 4) {
      int s0 = s_src[k];
      float c0 = s_coef[k][hd];
      uint2 u = *(const uint2*)(feat + (size_t)s0 * 256 + lane * 4);
      float2 f01 = __half22float2(*(__half2*)&u.x), f23 = __half22float2(*(__half2*)&u.y);
      ac0 = fmaf(c0, f01.x, ac0); ac1 = fmaf(c0, f01.y, ac1);
      ac2 = fmaf(c0, f23.x, ac2); ac3 = fmaf(c0, f23.y, ac3);
    }
  }
  red[wv][lane * 4 + 0] = ac0;
  red[wv][lane * 4 + 1] = ac1;
  red[wv][lane * 4 + 2] = ac2;
  red[wv][lane * 4 + 3] = ac3;
  __syncthreads();
  float dn = sdn[tid >> 6];
  float invd = (dn != 0.f) ? 1.f / dn : 0.f;
  float v = (red[0][tid] + red[1][tid] + red[2][tid] + red[3][tid]) * invd + bias[tid];
  gat[(size_t)n * 256 + tid] = __float2half_rn(v);
  vbuf[tid] = v;
  __syncthreads();

  // fused projection: wave wv owns outputs q = wv*4..wv*4+3  (q<8 -> gt[j=q], else gb[j=q-8])
  {
    float p[4] = {0.f, 0.f, 0.f, 0.f};
    float f[4];
#pragma unroll
    for (int r = 0; r < 4; ++r) f[r] = vbuf[lane * 4 + r];
#pragma unroll
    for (int qq = 0; qq < 4; ++qq) {
      int q = wv * 4 + qq;
      const float* Wm = (q < 8) ? Wt : Wb;
      int j = q & 7;
#pragma unroll
      for (int r = 0; r < 4; ++r)
        p[qq] = fmaf(f[r], Wm[(size_t)(lane * 4 + r) * 8 + j], p[qq]);
    }
#pragma unroll
    for (int o = 32; o >= 1; o >>= 1)
#pragma unroll
      for (int qq = 0; qq < 4; ++qq) p[qq] += __shfl_xor(p[qq], o, 64);
    if (lane == 0) {
#pragma unroll
      for (int qq = 0; qq < 4; ++qq) {
        int q = wv * 4 + qq;
        if (q < 8) gt[(size_t)n * 8 + q] = p[qq];
        else       gb[(size_t)n * 8 + (q - 8)] = p[qq];
      }
    }
  }
}

// ============== enhance: wave-per-node; rank + tiny gt/gb gathers ==============
__global__ __launch_bounds__(256)
void enhance_pool_kernel(const int* __restrict__ nbr_idx, const float* __restrict__ nbr_w,
                         const float* __restrict__ gt, const float* __restrict__ gb,
                         const float* __restrict__ bt, const float* __restrict__ bb,
                         float* __restrict__ tvec, float* __restrict__ bvec, int n_nodes)
{
  int n = (blockIdx.x * 256 + threadIdx.x) >> 6;
  int lane = threadIdx.x & 63;
  if (n >= n_nodes) return;
  const int l16 = lane & 15;

  float w = nbr_w[(size_t)n * 16 + l16];
  int idx = nbr_idx[(size_t)n * 16 + l16];

  int rhi = 0, rlo = 0;
#pragma unroll
  for (int i = 0; i < 16; ++i) {
    float wi = __shfl(w, i, 64);
    rhi += (wi > w) || (wi == w && i < l16);
    rlo += (wi < w) || (wi == w && i < l16);
  }

  int rows[7];
#pragma unroll
  for (int q = 0; q < 5; ++q) {
    unsigned long long m = __ballot(lane < 16 && rhi == q);
    rows[q] = __shfl(idx, __ffsll(m) - 1, 64);
  }
#pragma unroll
  for (int q = 0; q < 2; ++q) {
    unsigned long long m = __ballot(lane < 16 && rlo == q);
    rows[5 + q] = __shfl(idx, __ffsll(m) - 1, 64);
  }

  int j = lane & 7;
  if (lane < 8) {
    float s = 0.f;
#pragma unroll
    for (int q = 0; q < 5; ++q) s += gt[(size_t)rows[q] * 8 + j];
    tvec[(size_t)n * 8 + j] = s * 0.2f + bt[j];
  } else if (lane < 16) {
    float s = gb[(size_t)rows[5] * 8 + j] + gb[(size_t)rows[6] * 8 + j];
    bvec[(size_t)n * 8 + j] = s * 0.5f + bb[j];
  }
}

extern "C" void kernel_launch(void* const* d_in, const int* in_sizes, int n_in,
                              void* d_out, int out_size, void* d_ws, size_t ws_size,
                              hipStream_t stream)
{
  const int N_ = N_NODES;
  const int E_ = N_EDGES;

  const float* h = (const float*)d_in[0];
  const float* Wt = (const float*)d_in[28];
  const float* bt = (const float*)d_in[29];
  const float* Wb = (const float*)d_in[30];
  const float* bb = (const float*)d_in[31];
  const float* Wp = (const float*)d_in[32];
  const float* bp = (const float*)d_in[33];
  float* out = (float*)d_out;

  char* wsb = (char*)d_ws;
  size_t o = 0;
  auto alloc = [&](size_t bytes) -> void* {
    void* p = wsb + o;
    o = (o + bytes + 255) & ~(size_t)255;
    return p;
  };
  f16*  hf    = (f16*)alloc((size_t)N_ * 256 * 2);
  f16*  feat  = (f16*)alloc((size_t)N_ * 256 * 2);
  f16*  gat   = (f16*)alloc((size_t)N_ * 256 * 2);
  f16*  WT    = (f16*)alloc((size_t)4 * 256 * 256 * 2);   // 3x W + WpT
  float* el     = (float*)alloc((size_t)N_ * 4 * 4);
  float* er     = (float*)alloc((size_t)N_ * 4 * 4);
  float* gt     = (float*)alloc((size_t)N_ * 8 * 4);
  float* gb     = (float*)alloc((size_t)N_ * 8 * 4);
  float* tvec   = (float*)alloc((size_t)N_ * 8 * 4);
  float* bvec   = (float*)alloc((size_t)N_ * 8 * 4);
  int*   off    = (int*)alloc((size_t)3 * (N_ + 1) * 4);
  int*   counts = (int*)alloc((size_t)3 * N_ * 4);
  unsigned short* ghist = (unsigned short*)alloc((size_t)3 * NB * N_ * 2);  // 11.5 MB
  unsigned short* rank16 = (unsigned short*)alloc((size_t)3 * E_ * 2);
  int2*  csr_pay = (int2*)alloc((size_t)3 * E_ * 8);
  (void)ws_size; (void)in_sizes; (void)n_in; (void)out_size;

  const int row_blocks = (N_ + 127) / 128;  // 235
  const int edge_blocks = (E_ + 255) / 256; // 1875
  const int wave_blocks = (N_ + 3) / 4;     // 7500

  const int* d_dst0 = (const int*)d_in[1 + 0 * 9 + 1];
  const int* d_dst1 = (const int*)d_in[1 + 1 * 9 + 1];
  const int* d_dst2 = (const int*)d_in[1 + 2 * 9 + 1];
  const int* d_src0 = (const int*)d_in[1 + 0 * 9 + 0];
  const int* d_src1 = (const int*)d_in[1 + 1 * 9 + 0];
  const int* d_src2 = (const int*)d_in[1 + 2 * 9 + 0];
  const float* d_ew0 = (const float*)d_in[1 + 0 * 9 + 2];
  const float* d_ew1 = (const float*)d_in[1 + 1 * 9 + 2];
  const float* d_ew2 = (const float*)d_in[1 + 2 * 9 + 2];

  // one-time conversions (independent of CSR build)
  convert_h_kernel<<<(N_ * 256 / 8 + 255) / 256, 256, 0, stream>>>(h, hf, N_ * 256 / 8);
  transpose_w_kernel<<<dim3(256, 4), 256, 0, stream>>>(
      (const float*)d_in[1 + 0 * 9 + 5], (const float*)d_in[1 + 1 * 9 + 5],
      (const float*)d_in[1 + 2 * 9 + 5], Wp, WT);
  f16* WpT = WT + (size_t)3 * 65536;

  // atomic-free CSR build (batched over etypes)
  hist_kernel<<<dim3(NB, 3), 512, 0, stream>>>(d_dst0, d_dst1, d_dst2, ghist, rank16);
  blockpfx_kernel<<<dim3((N_ + 255) / 256, 3), 256, 0, stream>>>(ghist, counts);
  scan_kernel<<<3, 1024, 0, stream>>>(counts, off, N_, E_);
  place_kernel<<<dim3(edge_blocks, 3), 256, 0, stream>>>(
      d_dst0, d_dst1, d_dst2, d_src0, d_src1, d_src2, d_ew0, d_ew1, d_ew2,
      off, ghist, rank16, csr_pay);

  for (int et = 0; et < 3; ++et) {
    const int base = 1 + et * 9;
    const int* nbr_idx = (const int*)d_in[base + 3];
    const float* nbr_w = (const float*)d_in[base + 4];
    const float* al = (const float*)d_in[base + 6];
    const float* ar = (const float*)d_in[base + 7];
    const float* b = (const float*)d_in[base + 8];

    gemm_mfma<0><<<dim3(row_blocks, 4), 256, 0, stream>>>(
        hf, WT + (size_t)et * 65536, feat, nullptr, N_, al, ar, el, er,
        nullptr, nullptr, nullptr, nullptr, nullptr, 256, 0);

    aggregate_kernel<<<N_, 256, 0, stream>>>(
        off + (size_t)et * (N_ + 1), csr_pay + (size_t)et * E_,
        el, er, (const __half*)feat, b, Wt, Wb, (__half*)gat, gt, gb);

    enhance_pool_kernel<<<wave_blocks, 256, 0, stream>>>(
        nbr_idx, nbr_w, gt, gb, bt, bb, tvec, bvec, N_);

    gemm_mfma<1><<<dim3(row_blocks, 4), 256, 0, stream>>>(
        gat, WpT, nullptr, out, N_, nullptr, nullptr, nullptr, nullptr,
        tvec, bvec, Wp + 256 * 256, Wp + 264 * 256, bp, 768, et * 256);
  }
}

// Round 9
// 501.056 us; speedup vs baseline: 3.8054x; 1.0792x over previous
//
#include <hip/hip_runtime.h>
#include <hip/hip_fp16.h>

#define N_NODES 30000
#define N_EDGES 480000
#define NB 64           // blocks per etype for counting sort
#define CHUNK 7500      // N_EDGES / NB  (< 65536 so u16 ranks/counts are safe)

typedef _Float16 f16;
typedef f16 f16x8 __attribute__((ext_vector_type(8)));
typedef float f32x4 __attribute__((ext_vector_type(4)));

// ================= one-time converts =================
__global__ void convert_h_kernel(const float* __restrict__ in, f16* __restrict__ out, int n8)
{
  int i = blockIdx.x * 256 + threadIdx.x;
  if (i >= n8) return;
  float4 a = *(const float4*)(in + (size_t)i * 8);
  float4 b = *(const float4*)(in + (size_t)i * 8 + 4);
  f16x8 v;
  v[0] = (f16)a.x; v[1] = (f16)a.y; v[2] = (f16)a.z; v[3] = (f16)a.w;
  v[4] = (f16)b.x; v[5] = (f16)b.y; v[6] = (f16)b.z; v[7] = (f16)b.w;
  *(f16x8*)(out + (size_t)i * 8) = v;
}

// out[m][n][k] = (f16) in_m[k][n], 4 matrices 256x256, blockIdx.y = m
__global__ void transpose_w_kernel(const float* __restrict__ s0, const float* __restrict__ s1,
                                   const float* __restrict__ s2, const float* __restrict__ s3,
                                   f16* __restrict__ out)
{
  int m = blockIdx.y;
  const float* in = (m == 0) ? s0 : (m == 1) ? s1 : (m == 2) ? s2 : s3;
  int t = blockIdx.x * 256 + threadIdx.x;   // 65536
  int n = t >> 8, k = t & 255;
  out[(size_t)m * 65536 + t] = (f16)in[k * 256 + n];
}

// ================= MFMA GEMM: 128x64 tile, B-in-LDS-once, A direct from global =================
// MODE 0: feat(f16) = A@B; epilogue el/er (col-tile == head)
// MODE 1: out(f32) = A@B + t@Wp1 + bo@Wp2 + bp, strided store
template<int MODE>
__global__ __launch_bounds__(256)
void gemm_mfma(const f16* __restrict__ A, const f16* __restrict__ BT,
               f16* __restrict__ Ch, float* __restrict__ Cf, int M,
               const float* __restrict__ al, const float* __restrict__ ar,
               float* __restrict__ el, float* __restrict__ er,
               const float* __restrict__ tvec, const float* __restrict__ bvec,
               const float* __restrict__ Wp1, const float* __restrict__ Wp2,
               const float* __restrict__ bp, int ldc, int coff)
{
  __shared__ alignas(16) f16 Bs[64][264];   // +8 f16 pad
  __shared__ float W1s[8][64];
  __shared__ float W2s[8][64];
  __shared__ float t_lds[128][8];
  __shared__ float b_lds[128][8];

  const int tid = threadIdx.x;
  const int lane = tid & 63, wv = tid >> 6;
  const int l15 = lane & 15, lq = lane >> 4;
  const int bm = blockIdx.x * 128;
  const int ct = blockIdx.y;
  const int bn = ct * 64;

  // stage B col-tile ONCE: 64 cols x 256 k (each uint4 = 8 f16)
#pragma unroll
  for (int i = 0; i < 8; ++i) {
    int seg = tid + i * 256;        // 0..2047
    int row = seg >> 5;             // 0..63  (32 segments of 8 f16 per row)
    int cs = (seg & 31) * 8;        // 0..248
    *(uint4*)&Bs[row][cs] = *(const uint4*)&BT[(size_t)(bn + row) * 256 + cs];
  }

  if (MODE == 1) {
    if (tid < 128) {
      int r = tid >> 4, c4 = (tid & 15) * 4;
      *(float4*)&W1s[r][c4] = *(const float4*)&Wp1[r * 256 + bn + c4];
    } else {
      int t2 = tid - 128;
      int r = t2 >> 4, c4 = (t2 & 15) * 4;
      *(float4*)&W2s[r][c4] = *(const float4*)&Wp2[r * 256 + bn + c4];
    }
    {
      int r = tid >> 1, c = (tid & 1) * 4;
      int row = bm + r;
      float4 tv = make_float4(0.f, 0.f, 0.f, 0.f), bv2 = tv;
      if (row < M) {
        tv  = *(const float4*)&tvec[(size_t)row * 8 + c];
        bv2 = *(const float4*)&bvec[(size_t)row * 8 + c];
      }
      *(float4*)&t_lds[r][c] = tv;
      *(float4*)&b_lds[r][c] = bv2;
    }
  }
  __syncthreads();

  const int r0 = bm + wv * 32 + l15;
  const int r1 = r0 + 16;
  const bool ok0 = r0 < M, ok1 = r1 < M;
  const f16* Arow0 = A + (size_t)r0 * 256;
  const f16* Arow1 = A + (size_t)r1 * 256;

  f32x4 acc[2][4] = {};

#pragma unroll
  for (int k0 = 0; k0 < 256; k0 += 32) {
    int ko = k0 + lq * 8;
    f16x8 a0 = {0, 0, 0, 0, 0, 0, 0, 0};
    f16x8 a1 = {0, 0, 0, 0, 0, 0, 0, 0};
    if (ok0) a0 = *(const f16x8*)(Arow0 + ko);
    if (ok1) a1 = *(const f16x8*)(Arow1 + ko);
#pragma unroll
    for (int nf = 0; nf < 4; ++nf) {
      f16x8 bf = *(const f16x8*)&Bs[nf * 16 + l15][ko];
      acc[0][nf] = __builtin_amdgcn_mfma_f32_16x16x32_f16(a0, bf, acc[0][nf], 0, 0, 0);
      acc[1][nf] = __builtin_amdgcn_mfma_f32_16x16x32_f16(a1, bf, acc[1][nf], 0, 0, 0);
    }
  }

  if (MODE == 0) {
    float alv[4], arv[4];
#pragma unroll
    for (int nf = 0; nf < 4; ++nf) {
      alv[nf] = al[bn + nf * 16 + l15];
      arv[nf] = ar[bn + nf * 16 + l15];
    }
#pragma unroll
    for (int m = 0; m < 2; ++m)
#pragma unroll
      for (int i = 0; i < 4; ++i) {
        int row = bm + wv * 32 + m * 16 + lq * 4 + i;
        float pe = 0.f, pr = 0.f;
#pragma unroll
        for (int nf = 0; nf < 4; ++nf) {
          pe = fmaf(acc[m][nf][i], alv[nf], pe);
          pr = fmaf(acc[m][nf][i], arv[nf], pr);
        }
#pragma unroll
        for (int o = 8; o >= 1; o >>= 1) {
          pe += __shfl_xor(pe, o, 64);
          pr += __shfl_xor(pr, o, 64);
        }
        if (row < M) {
          if (l15 == 0) {
            el[row * 4 + ct] = pe;
            er[row * 4 + ct] = pr;
          }
#pragma unroll
          for (int nf = 0; nf < 4; ++nf)
            Ch[(size_t)row * 256 + bn + nf * 16 + l15] = (f16)acc[m][nf][i];
        }
      }
  } else {
    float bpv[4];
#pragma unroll
    for (int nf = 0; nf < 4; ++nf) bpv[nf] = bp[bn + nf * 16 + l15];
#pragma unroll
    for (int m = 0; m < 2; ++m)
#pragma unroll
      for (int i = 0; i < 4; ++i) {
        int rl = wv * 32 + m * 16 + lq * 4 + i;
        int row = bm + rl;
        if (row >= M) continue;
#pragma unroll
        for (int nf = 0; nf < 4; ++nf) {
          int c = nf * 16 + l15;
          float v = acc[m][nf][i] + bpv[nf];
#pragma unroll
          for (int k = 0; k < 8; ++k) {
            v = fmaf(t_lds[rl][k], W1s[k][c], v);
            v = fmaf(b_lds[rl][k], W2s[k][c], v);
          }
          Cf[(size_t)row * ldc + coff + bn + c] = v;
        }
      }
  }
}

// ============== CSR build pass 1: LDS histogram + per-edge local rank ==============
__global__ __launch_bounds__(512)
void hist_kernel(const int* __restrict__ d0, const int* __restrict__ d1,
                 const int* __restrict__ d2, unsigned short* __restrict__ ghist,
                 unsigned short* __restrict__ rank16)
{
  __shared__ unsigned int h32[N_NODES / 2];
  int et = blockIdx.y, b = blockIdx.x, tid = threadIdx.x;
  const int* dst = (et == 0) ? d0 : (et == 1) ? d1 : d2;
  for (int i = tid; i < N_NODES / 2; i += 512) h32[i] = 0u;
  __syncthreads();
  int e0 = b * CHUNK;
  for (int i = tid; i < CHUNK; i += 512) {
    int e = e0 + i;
    int d = dst[e];
    unsigned int sh = (d & 1) * 16;
    unsigned int old = atomicAdd(&h32[d >> 1], 1u << sh);
    rank16[(size_t)et * N_EDGES + e] = (unsigned short)((old >> sh) & 0xFFFFu);
  }
  __syncthreads();
  unsigned short* gh = ghist + ((size_t)(et * NB + b)) * N_NODES;
  for (int d = tid; d < N_NODES; d += 512)
    gh[d] = (unsigned short)((h32[d >> 1] >> ((d & 1) * 16)) & 0xFFFFu);
}

// ============== pass 2: per-dst exclusive prefix over NB blocks + totals ==============
__global__ __launch_bounds__(256)
void blockpfx_kernel(unsigned short* __restrict__ ghist, int* __restrict__ counts)
{
  int d = blockIdx.x * 256 + threadIdx.x;
  int et = blockIdx.y;
  if (d >= N_NODES) return;
  int running = 0;
#pragma unroll
  for (int b = 0; b < NB; ++b) {
    size_t idx = ((size_t)(et * NB + b)) * N_NODES + d;
    int v = ghist[idx];
    ghist[idx] = (unsigned short)running;
    running += v;
  }
  counts[et * N_NODES + d] = running;
}

// ============== batched scan (blockIdx.x = etype) ==============
__global__ __launch_bounds__(1024)
void scan_kernel(int* __restrict__ cc_all, int* __restrict__ off_all, int n, int total)
{
  int et = blockIdx.x;
  int* cc = cc_all + (size_t)et * n;
  int* off = off_all + (size_t)et * (n + 1);
  __shared__ int wsum[16];
  __shared__ int woff[16];
  __shared__ int s_carry, s_chunk;
  int tid = threadIdx.x;
  int lane = tid & 63, wid = tid >> 6;
  if (tid == 0) s_carry = 0;
  __syncthreads();
  for (int base = 0; base < n; base += 1024) {
    int i = base + tid;
    int v = (i < n) ? cc[i] : 0;
    int x = v;
#pragma unroll
    for (int s = 1; s < 64; s <<= 1) {
      int y = __shfl_up(x, s, 64);
      if (lane >= s) x += y;
    }
    if (lane == 63) wsum[wid] = x;
    __syncthreads();
    if (wid == 0 && lane < 16) {
      int ws_ = wsum[lane];
      int xx = ws_;
#pragma unroll
      for (int s = 1; s < 16; s <<= 1) {
        int y = __shfl_up(xx, s, 64);
        if (lane >= s) xx += y;
      }
      woff[lane] = xx - ws_;
      if (lane == 15) s_chunk = xx;
    }
    __syncthreads();
    int excl = s_carry + woff[wid] + (x - v);
    if (i < n) { off[i] = excl; cc[i] = excl; }
    __syncthreads();
    if (tid == 0) s_carry += s_chunk;
    __syncthreads();
  }
  if (tid == 0) off[n] = total;
}

// ============== pass 4: place packed payload (no atomics, single 8B scatter) ==============
__global__ __launch_bounds__(256)
void place_kernel(const int* __restrict__ d0, const int* __restrict__ d1,
                  const int* __restrict__ d2,
                  const int* __restrict__ s0, const int* __restrict__ s1,
                  const int* __restrict__ s2,
                  const float* __restrict__ w0, const float* __restrict__ w1,
                  const float* __restrict__ w2,
                  const int* __restrict__ off, const unsigned short* __restrict__ ghist,
                  const unsigned short* __restrict__ rank16,
                  int2* __restrict__ csr_pay)
{
  int e = blockIdx.x * 256 + threadIdx.x;
  if (e >= N_EDGES) return;
  int et = blockIdx.y;
  const int* dst = (et == 0) ? d0 : (et == 1) ? d1 : d2;
  const int* src = (et == 0) ? s0 : (et == 1) ? s1 : s2;
  const float* ew = (et == 0) ? w0 : (et == 1) ? w1 : w2;
  int d = dst[e];
  int b = e / CHUNK;
  int pos = off[et * (N_NODES + 1) + d]
          + (int)ghist[((size_t)(et * NB + b)) * N_NODES + d]
          + (int)rank16[(size_t)et * N_EDGES + e];
  csr_pay[(size_t)et * N_EDGES + pos] = make_int2(src[e], __float_as_int(ew[e]));
}

// ============== wave-per-node aggregation (barrier-free) + fused gt/gb projection ==============
__global__ __launch_bounds__(256)
void aggregate_kernel(const int* __restrict__ off, const int2* __restrict__ csr_pay,
                      const float* __restrict__ el, const float* __restrict__ er,
                      const __half* __restrict__ feat, const float* __restrict__ bias,
                      const float* __restrict__ Wt, const float* __restrict__ Wb,
                      __half* __restrict__ gat, float* __restrict__ gt, float* __restrict__ gb,
                      int n_nodes)
{
  int tid = threadIdx.x;
  int lane = tid & 63, wv = tid >> 6;
  int n = blockIdx.x * 4 + wv;
  if (n >= n_nodes) return;
  int hd = lane >> 4;                    // head of this lane's 4-column slice

  __shared__ int   s_src[4][16];
  __shared__ float s_cf[4][16][4];       // ex * ew
  __shared__ float s_ex[4][16][4];       // ex (for denom)

  int e0 = off[n], e1 = off[n + 1];
  float4 er4 = *(const float4*)&er[(size_t)n * 4];
  float4 bv = *(const float4*)&bias[lane * 4];
  float ac0 = 0.f, ac1 = 0.f, ac2 = 0.f, ac3 = 0.f, dn = 0.f;

  for (int base = e0; base < e1; base += 16) {
    int cnt = min(16, e1 - base);
    if (lane < cnt) {
      int2 pay = csr_pay[base + lane];
      int s = pay.x;
      float w = __int_as_float(pay.y);
      s_src[wv][lane] = s;
      float4 l4 = *(const float4*)&el[(size_t)s * 4];
      float v0 = l4.x + er4.x; v0 = v0 > 0.f ? v0 : 0.2f * v0;
      float v1 = l4.y + er4.y; v1 = v1 > 0.f ? v1 : 0.2f * v1;
      float v2 = l4.z + er4.z; v2 = v2 > 0.f ? v2 : 0.2f * v2;
      float v3 = l4.w + er4.w; v3 = v3 > 0.f ? v3 : 0.2f * v3;
      float x0 = __expf(v0), x1 = __expf(v1), x2 = __expf(v2), x3 = __expf(v3);
      s_ex[wv][lane][0] = x0; s_ex[wv][lane][1] = x1;
      s_ex[wv][lane][2] = x2; s_ex[wv][lane][3] = x3;
      s_cf[wv][lane][0] = x0 * w; s_cf[wv][lane][1] = x1 * w;
      s_cf[wv][lane][2] = x2 * w; s_cf[wv][lane][3] = x3 * w;
    }
    __builtin_amdgcn_wave_barrier();   // wave-synchronous: order LDS write->read (HW waitcnt handles visibility)
    int k = 0;
    for (; k + 3 < cnt; k += 4) {
      int sA = s_src[wv][k], sB = s_src[wv][k + 1], sC = s_src[wv][k + 2], sD = s_src[wv][k + 3];
      float cA = s_cf[wv][k][hd], cB = s_cf[wv][k + 1][hd];
      float cC = s_cf[wv][k + 2][hd], cD = s_cf[wv][k + 3][hd];
      dn += s_ex[wv][k][hd] + s_ex[wv][k + 1][hd] + s_ex[wv][k + 2][hd] + s_ex[wv][k + 3][hd];
      uint2 uA = *(const uint2*)(feat + (size_t)sA * 256 + lane * 4);
      uint2 uB = *(const uint2*)(feat + (size_t)sB * 256 + lane * 4);
      uint2 uC = *(const uint2*)(feat + (size_t)sC * 256 + lane * 4);
      uint2 uD = *(const uint2*)(feat + (size_t)sD * 256 + lane * 4);
      float2 A01 = __half22float2(*(__half2*)&uA.x), A23 = __half22float2(*(__half2*)&uA.y);
      float2 B01 = __half22float2(*(__half2*)&uB.x), B23 = __half22float2(*(__half2*)&uB.y);
      float2 C01 = __half22float2(*(__half2*)&uC.x), C23 = __half22float2(*(__half2*)&uC.y);
      float2 D01 = __half22float2(*(__half2*)&uD.x), D23 = __half22float2(*(__half2*)&uD.y);
      ac0 = fmaf(cA, A01.x, ac0); ac1 = fmaf(cA, A01.y, ac1);
      ac2 = fmaf(cA, A23.x, ac2); ac3 = fmaf(cA, A23.y, ac3);
      ac0 = fmaf(cB, B01.x, ac0); ac1 = fmaf(cB, B01.y, ac1);
      ac2 = fmaf(cB, B23.x, ac2); ac3 = fmaf(cB, B23.y, ac3);
      ac0 = fmaf(cC, C01.x, ac0); ac1 = fmaf(cC, C01.y, ac1);
      ac2 = fmaf(cC, C23.x, ac2); ac3 = fmaf(cC, C23.y, ac3);
      ac0 = fmaf(cD, D01.x, ac0); ac1 = fmaf(cD, D01.y, ac1);
      ac2 = fmaf(cD, D23.x, ac2); ac3 = fmaf(cD, D23.y, ac3);
    }
    for (; k < cnt; ++k) {
      int s0 = s_src[wv][k];
      float c0 = s_cf[wv][k][hd];
      dn += s_ex[wv][k][hd];
      uint2 u = *(const uint2*)(feat + (size_t)s0 * 256 + lane * 4);
      float2 f01 = __half22float2(*(__half2*)&u.x), f23 = __half22float2(*(__half2*)&u.y);
      ac0 = fmaf(c0, f01.x, ac0); ac1 = fmaf(c0, f01.y, ac1);
      ac2 = fmaf(c0, f23.x, ac2); ac3 = fmaf(c0, f23.y, ac3);
    }
    __builtin_amdgcn_wave_barrier();   // don't let next chunk's writes sink above these reads
  }

  float invd = (dn != 0.f) ? 1.f / dn : 0.f;
  float v0 = ac0 * invd + bv.x;
  float v1 = ac1 * invd + bv.y;
  float v2 = ac2 * invd + bv.z;
  float v3 = ac3 * invd + bv.w;

  __half2 h01 = __floats2half2_rn(v0, v1);
  __half2 h23 = __floats2half2_rn(v2, v3);
  uint2 st;
  st.x = *(unsigned int*)&h01;
  st.y = *(unsigned int*)&h23;
  *(uint2*)&gat[(size_t)n * 256 + lane * 4] = st;

  // fused projection: p[0..7] = gt partials, p[8..15] = gb partials (in-wave)
  float p[16];
#pragma unroll
  for (int j = 0; j < 16; ++j) p[j] = 0.f;
  float fv[4] = {v0, v1, v2, v3};
#pragma unroll
  for (int r = 0; r < 4; ++r) {
    int c = lane * 4 + r;
    const float* wtr = &Wt[(size_t)c * 8];
    const float* wbr = &Wb[(size_t)c * 8];
#pragma unroll
    for (int j = 0; j < 8; ++j) {
      p[j]     = fmaf(fv[r], wtr[j], p[j]);
      p[8 + j] = fmaf(fv[r], wbr[j], p[8 + j]);
    }
  }
#pragma unroll
  for (int o = 32; o >= 1; o >>= 1) {
#pragma unroll
    for (int j = 0; j < 16; ++j) p[j] += __shfl_xor(p[j], o, 64);
  }
  if (lane == 0) {
#pragma unroll
    for (int j = 0; j < 8; ++j) {
      gt[(size_t)n * 8 + j] = p[j];
      gb[(size_t)n * 8 + j] = p[8 + j];
    }
  }
}

// ============== enhance: wave-per-node; rank + tiny gt/gb gathers ==============
__global__ __launch_bounds__(256)
void enhance_pool_kernel(const int* __restrict__ nbr_idx, const float* __restrict__ nbr_w,
                         const float* __restrict__ gt, const float* __restrict__ gb,
                         const float* __restrict__ bt, const float* __restrict__ bb,
                         float* __restrict__ tvec, float* __restrict__ bvec, int n_nodes)
{
  int n = (blockIdx.x * 256 + threadIdx.x) >> 6;
  int lane = threadIdx.x & 63;
  if (n >= n_nodes) return;
  const int l16 = lane & 15;

  float w = nbr_w[(size_t)n * 16 + l16];
  int idx = nbr_idx[(size_t)n * 16 + l16];

  int rhi = 0, rlo = 0;
#pragma unroll
  for (int i = 0; i < 16; ++i) {
    float wi = __shfl(w, i, 64);
    rhi += (wi > w) || (wi == w && i < l16);
    rlo += (wi < w) || (wi == w && i < l16);
  }

  int rows[7];
#pragma unroll
  for (int q = 0; q < 5; ++q) {
    unsigned long long m = __ballot(lane < 16 && rhi == q);
    rows[q] = __shfl(idx, __ffsll(m) - 1, 64);
  }
#pragma unroll
  for (int q = 0; q < 2; ++q) {
    unsigned long long m = __ballot(lane < 16 && rlo == q);
    rows[5 + q] = __shfl(idx, __ffsll(m) - 1, 64);
  }

  int j = lane & 7;
  if (lane < 8) {
    float s = 0.f;
#pragma unroll
    for (int q = 0; q < 5; ++q) s += gt[(size_t)rows[q] * 8 + j];
    tvec[(size_t)n * 8 + j] = s * 0.2f + bt[j];
  } else if (lane < 16) {
    float s = gb[(size_t)rows[5] * 8 + j] + gb[(size_t)rows[6] * 8 + j];
    bvec[(size_t)n * 8 + j] = s * 0.5f + bb[j];
  }
}

extern "C" void kernel_launch(void* const* d_in, const int* in_sizes, int n_in,
                              void* d_out, int out_size, void* d_ws, size_t ws_size,
                              hipStream_t stream)
{
  const int N_ = N_NODES;
  const int E_ = N_EDGES;

  const float* h = (const float*)d_in[0];
  const float* Wt = (const float*)d_in[28];
  const float* bt = (const float*)d_in[29];
  const float* Wb = (const float*)d_in[30];
  const float* bb = (const float*)d_in[31];
  const float* Wp = (const float*)d_in[32];
  const float* bp = (const float*)d_in[33];
  float* out = (float*)d_out;

  char* wsb = (char*)d_ws;
  size_t o = 0;
  auto alloc = [&](size_t bytes) -> void* {
    void* p = wsb + o;
    o = (o + bytes + 255) & ~(size_t)255;
    return p;
  };
  f16*  hf    = (f16*)alloc((size_t)N_ * 256 * 2);
  f16*  feat  = (f16*)alloc((size_t)N_ * 256 * 2);
  f16*  gat   = (f16*)alloc((size_t)N_ * 256 * 2);
  f16*  WT    = (f16*)alloc((size_t)4 * 256 * 256 * 2);   // 3x W + WpT
  float* el     = (float*)alloc((size_t)N_ * 4 * 4);
  float* er     = (float*)alloc((size_t)N_ * 4 * 4);
  float* gt     = (float*)alloc((size_t)N_ * 8 * 4);
  float* gb     = (float*)alloc((size_t)N_ * 8 * 4);
  float* tvec   = (float*)alloc((size_t)N_ * 8 * 4);
  float* bvec   = (float*)alloc((size_t)N_ * 8 * 4);
  int*   off    = (int*)alloc((size_t)3 * (N_ + 1) * 4);
  int*   counts = (int*)alloc((size_t)3 * N_ * 4);
  unsigned short* ghist = (unsigned short*)alloc((size_t)3 * NB * N_ * 2);  // 11.5 MB
  unsigned short* rank16 = (unsigned short*)alloc((size_t)3 * E_ * 2);
  int2*  csr_pay = (int2*)alloc((size_t)3 * E_ * 8);
  (void)ws_size; (void)in_sizes; (void)n_in; (void)out_size;

  const int row_blocks = (N_ + 127) / 128;  // 235
  const int edge_blocks = (E_ + 255) / 256; // 1875
  const int wave_blocks = (N_ + 3) / 4;     // 7500

  const int* d_dst0 = (const int*)d_in[1 + 0 * 9 + 1];
  const int* d_dst1 = (const int*)d_in[1 + 1 * 9 + 1];
  const int* d_dst2 = (const int*)d_in[1 + 2 * 9 + 1];
  const int* d_src0 = (const int*)d_in[1 + 0 * 9 + 0];
  const int* d_src1 = (const int*)d_in[1 + 1 * 9 + 0];
  const int* d_src2 = (const int*)d_in[1 + 2 * 9 + 0];
  const float* d_ew0 = (const float*)d_in[1 + 0 * 9 + 2];
  const float* d_ew1 = (const float*)d_in[1 + 1 * 9 + 2];
  const float* d_ew2 = (const float*)d_in[1 + 2 * 9 + 2];

  // one-time conversions (independent of CSR build)
  convert_h_kernel<<<(N_ * 256 / 8 + 255) / 256, 256, 0, stream>>>(h, hf, N_ * 256 / 8);
  transpose_w_kernel<<<dim3(256, 4), 256, 0, stream>>>(
      (const float*)d_in[1 + 0 * 9 + 5], (const float*)d_in[1 + 1 * 9 + 5],
      (const float*)d_in[1 + 2 * 9 + 5], Wp, WT);
  f16* WpT = WT + (size_t)3 * 65536;

  // atomic-free CSR build (batched over etypes)
  hist_kernel<<<dim3(NB, 3), 512, 0, stream>>>(d_dst0, d_dst1, d_dst2, ghist, rank16);
  blockpfx_kernel<<<dim3((N_ + 255) / 256, 3), 256, 0, stream>>>(ghist, counts);
  scan_kernel<<<3, 1024, 0, stream>>>(counts, off, N_, E_);
  place_kernel<<<dim3(edge_blocks, 3), 256, 0, stream>>>(
      d_dst0, d_dst1, d_dst2, d_src0, d_src1, d_src2, d_ew0, d_ew1, d_ew2,
      off, ghist, rank16, csr_pay);

  for (int et = 0; et < 3; ++et) {
    const int base = 1 + et * 9;
    const int* nbr_idx = (const int*)d_in[base + 3];
    const float* nbr_w = (const float*)d_in[base + 4];
    const float* al = (const float*)d_in[base + 6];
    const float* ar = (const float*)d_in[base + 7];
    const float* b = (const float*)d_in[base + 8];

    gemm_mfma<0><<<dim3(row_blocks, 4), 256, 0, stream>>>(
        hf, WT + (size_t)et * 65536, feat, nullptr, N_, al, ar, el, er,
        nullptr, nullptr, nullptr, nullptr, nullptr, 256, 0);

    aggregate_kernel<<<wave_blocks, 256, 0, stream>>>(
        off + (size_t)et * (N_ + 1), csr_pay + (size_t)et * E_,
        el, er, (const __half*)feat, b, Wt, Wb, (__half*)gat, gt, gb, N_);

    enhance_pool_kernel<<<wave_blocks, 256, 0, stream>>>(
        nbr_idx, nbr_w, gt, gb, bt, bb, tvec, bvec, N_);

    gemm_mfma<1><<<dim3(row_blocks, 4), 256, 0, stream>>>(
        gat, WpT, nullptr, out, N_, nullptr, nullptr, nullptr, nullptr,
        tvec, bvec, Wp + 256 * 256, Wp + 264 * 256, bp, 768, et * 256);
  }
}